// Round 10
// baseline (616.159 us; speedup 1.0000x reference)
//
#include <hip/hip_runtime.h>

#define NN 4096
#define CC 256
#define EE 131072
#define KT 32

typedef unsigned short ushort_t;
typedef __attribute__((ext_vector_type(8))) short short8;   // bf16x8 (4 VGPRs)
typedef __attribute__((ext_vector_type(4))) float float4v;  // fp32x4 acc

__device__ __forceinline__ ushort_t f2bf(float x) {
    union { float f; unsigned u; } a; a.f = x;
    unsigned r = (a.u + 0x7FFF + ((a.u >> 16) & 1)) >> 16;   // RNE
    return (ushort_t)r;
}
__device__ __forceinline__ float bf2f(ushort_t b) {
    union { float f; unsigned u; } a; a.u = ((unsigned)b) << 16;
    return a.f;
}
// fast exp: v_exp_f32 is exp2 (~1 ulp); inputs bounded |x| < ~15 here
__device__ __forceinline__ float fexp(float x) {
#if __has_builtin(__builtin_amdgcn_exp2f)
    return __builtin_amdgcn_exp2f(x * 1.4426950408889634f);
#else
    return exp2f(x * 1.4426950408889634f);
#endif
}

// ---------------- workspace layout (float slots) ----------------
constexpr size_t OFF_EPT  = 0;                         // exp(pe logits)^T [j][i] 4096x4096
constexpr size_t OFF_EST  = OFF_EPT + 16777216;        // exp(se logits)^T
// --- zero region ---
constexpr size_t OFF_LP   = OFF_EST + 16777216;        // -> ag/Lp after invrows
constexpr size_t OFF_LS   = OFF_LP + 4096;
constexpr size_t OFF_LA   = OFF_LS + 4096;
constexpr size_t OFF_ECNT = OFF_LA + 4096;             // int: in-degree per dst
constexpr size_t OFF_GCNT = OFF_ECNT + 4096;           // int: global-entry count per row i
constexpr size_t OFF_ADJ  = OFF_GCNT + 4096;           // 524288 u32 adjacency bitmap [dst][src]
constexpr size_t ZERO_END = OFF_ADJ + 524288;
// --- non-zeroed ---
constexpr size_t OFF_XM   = ZERO_END;                  // pe_m, se_m, ae_m fp32 (3 x 4096x256)
constexpr size_t OFF_QK   = OFF_XM + 3*1048576;        // 12 bf16 arrays: (qh,ql,kh,kl) x 3 branch
constexpr size_t OFF_WEXP = OFF_QK + 6*1048576;        // 3*E exp(edge logits)
constexpr size_t OFF_HS   = OFF_WEXP + 3*131072;       // 3*4096
constexpr size_t OFF_HD   = OFF_HS + 12288;
constexpr size_t OFF_WSD  = OFF_HD + 12288;            // 6*256 fused gat vecs
constexpr size_t OFF_TKI  = OFF_WSD + 1536;            // topk indices (int) 4096*32
constexpr size_t OFF_TKV  = OFF_TKI + 131072;          // topk sample values
constexpr size_t OFF_GN   = OFF_TKV + 131072;          // normalized g values
constexpr size_t OFF_EOFF = OFF_GN + 131072;           // int 4097 csr offsets (edges by dst)
constexpr size_t OFF_ECUR = OFF_EOFF + 4097;           // int 4096 fill cursors
constexpr size_t OFF_ELST = OFF_ECUR + 4096;           // int E edge ids
constexpr size_t OFF_GOFF = OFF_ELST + 131072;         // int 4097
constexpr size_t OFF_GCUR = OFF_GOFF + 4097;           // int 4096
constexpr size_t OFF_GLST = OFF_GCUR + 4096;           // int N*K entry ids
constexpr size_t OFF_WLT  = OFF_GLST + 131072;         // combined [wloc;wglb]^T hi+lo (262144 shorts)
constexpr size_t WS_FLOATS = OFF_WLT + 131072;         // ~189 MiB

// -- transient bf16 sub-layouts (short offsets) --
constexpr size_t SH_XINH = 0;                          // 3 x 1M
constexpr size_t SH_XINL = 3145728;
constexpr size_t SH_HIDH = 6291456;                    // 3 x 2M
constexpr size_t SH_HIDL = 12582912;
constexpr size_t SH_XMH  = 18874368;                   // 3 x 1M
constexpr size_t SH_XML  = 22020096;
constexpr size_t SH_WT   = 25165824;                   // per-branch transposed weights
constexpr size_t WT_BR   = 786432;                     // shorts per branch

// ---------------- batched weight transpose + split ----------------
struct TArgs {
    const float* s[14]; ushort_t* h[14]; ushort_t* l[14];
    int nshift[14]; int total[14]; int kstride[14]; int koff[14];
};

__global__ __launch_bounds__(256)
void wtrans_k(TArgs a)
{
    int z = blockIdx.z;
    int idx = blockIdx.x * 256 + threadIdx.x;
    if (idx >= a.total[z]) return;
    int n = idx & ((1 << a.nshift[z]) - 1);
    int k = idx >> a.nshift[z];
    float v = a.s[z][idx];
    ushort_t hh = f2bf(v);
    size_t o = (size_t)n * a.kstride[z] + a.koff[z] + k;
    a.h[z][o] = hh;
    a.l[z][o] = f2bf(v - bf2f(hh));
}

// ---------------- activation split: h/l bf16 copies ----------------
__global__ __launch_bounds__(256)
void split3_k(const float* s0, const float* s1, const float* s2,
              ushort_t* hb, ushort_t* lb, size_t nper)
{
    int z = blockIdx.z;
    const float* s = (z == 0) ? s0 : (z == 1) ? s1 : s2;
    ushort_t* h = hb + (size_t)z * nper;
    ushort_t* l = lb + (size_t)z * nper;
    size_t i = (size_t)(blockIdx.x * 256 + threadIdx.x) * 4;
    float4 v = *(const float4*)(s + i);
    ushort_t h0 = f2bf(v.x), h1 = f2bf(v.y), h2 = f2bf(v.z), h3 = f2bf(v.w);
    ushort_t l0 = f2bf(v.x - bf2f(h0)), l1 = f2bf(v.y - bf2f(h1));
    ushort_t l2 = f2bf(v.z - bf2f(h2)), l3 = f2bf(v.w - bf2f(h3));
    uint2 hw, lw;
    hw.x = (unsigned)h0 | ((unsigned)h1 << 16); hw.y = (unsigned)h2 | ((unsigned)h3 << 16);
    lw.x = (unsigned)l0 | ((unsigned)l1 << 16); lw.y = (unsigned)l2 | ((unsigned)l3 << 16);
    *(uint2*)(h + i) = hw;
    *(uint2*)(l + i) = lw;
}

// ---------------- batched bf16x3 MFMA GEMM: C[z] = A[z] @ B[z]^T ----------------
// 128x64 tile: wave w computes rows w*32..w*32+31 x all 64 cols.
// MFMA:ds_read ratio 2.0 (vs 1.5 at 64x64). XOR swizzle keeps LDS conflict-free.
struct MArgs {
    const ushort_t* Ah[6]; const ushort_t* Al[6];
    const ushort_t* Bh[6]; const ushort_t* Bl[6];
    const float* bias[6];
    float* Cf[6]; ushort_t* Ch[6]; ushort_t* Cl[6];
};

template<int RELU>
__global__ __launch_bounds__(256)
void mgemm_k(MArgs a, int N, int K)
{
    __shared__ ushort_t SA[2][128 * 32];
    __shared__ ushort_t SB[2][64 * 32];

    const int z = blockIdx.z;
    const int t = threadIdx.x, wave = t >> 6, lane = t & 63;
    const int lrow = lane & 15, lquad = lane >> 4;

    const ushort_t* src = (wave == 0) ? a.Ah[z] : (wave == 1) ? a.Al[z]
                        : (wave == 2) ? a.Bh[z] : a.Bl[z];
    ushort_t* dst = (wave == 0) ? &SA[0][0] : (wave == 1) ? &SA[1][0]
                  : (wave == 2) ? &SB[0][0] : &SB[1][0];
    const int rbase = (wave < 2) ? blockIdx.x * 128 : blockIdx.y * 64;
    const int sr = lane >> 2, sq = lane & 3;
    const int gsq = sq ^ ((sr >> 1) & 3);          // staging-side swizzle

    float4v acc[2][4] = {};

    for (int k0 = 0; k0 < K; k0 += 32) {
        if (wave < 2) {
            #pragma unroll
            for (int it = 0; it < 8; ++it) {
                const ushort_t* g = src + (size_t)(rbase + it * 16 + sr) * K + k0 + gsq * 8;
                __builtin_amdgcn_global_load_lds(
                    (const __attribute__((address_space(1))) void*)g,
                    (__attribute__((address_space(3))) void*)(dst + it * 512),
                    16, 0, 0);
            }
        } else {
            #pragma unroll
            for (int it = 0; it < 4; ++it) {
                const ushort_t* g = src + (size_t)(rbase + it * 16 + sr) * K + k0 + gsq * 8;
                __builtin_amdgcn_global_load_lds(
                    (const __attribute__((address_space(1))) void*)g,
                    (__attribute__((address_space(3))) void*)(dst + it * 512),
                    16, 0, 0);
            }
        }
        __syncthreads();

        short8 fAh[2], fAl[2], fBh[4], fBl[4];
        #pragma unroll
        for (int mt = 0; mt < 2; ++mt) {
            int ra = wave * 32 + mt * 16 + lrow;
            int ca = (lquad ^ ((ra >> 1) & 3)) * 8;
            fAh[mt] = *(const short8*)&SA[0][ra * 32 + ca];
            fAl[mt] = *(const short8*)&SA[1][ra * 32 + ca];
        }
        #pragma unroll
        for (int nt = 0; nt < 4; ++nt) {
            int rb = nt * 16 + lrow;
            int cb = (lquad ^ ((rb >> 1) & 3)) * 8;
            fBh[nt] = *(const short8*)&SB[0][rb * 32 + cb];
            fBl[nt] = *(const short8*)&SB[1][rb * 32 + cb];
        }
        #pragma unroll
        for (int mt = 0; mt < 2; ++mt)
            #pragma unroll
            for (int nt = 0; nt < 4; ++nt) {
                acc[mt][nt] = __builtin_amdgcn_mfma_f32_16x16x32_bf16(fAh[mt], fBh[nt], acc[mt][nt], 0, 0, 0);
                acc[mt][nt] = __builtin_amdgcn_mfma_f32_16x16x32_bf16(fAh[mt], fBl[nt], acc[mt][nt], 0, 0, 0);
                acc[mt][nt] = __builtin_amdgcn_mfma_f32_16x16x32_bf16(fAl[mt], fBh[nt], acc[mt][nt], 0, 0, 0);
            }
        __syncthreads();
    }

    const float* bias = a.bias[z];
    float* Cf = a.Cf[z];
    ushort_t* Ch = a.Ch[z]; ushort_t* Cl = a.Cl[z];
    const int i0w = blockIdx.x * 128 + wave * 32, j0w = blockIdx.y * 64;
    #pragma unroll
    for (int mt = 0; mt < 2; ++mt) {
        const int ib = i0w + mt * 16 + lquad * 4;
        #pragma unroll
        for (int nt = 0; nt < 4; ++nt) {
            const int j = j0w + nt * 16 + lrow;
            float bj = bias ? bias[j] : 0.f;
            #pragma unroll
            for (int r = 0; r < 4; ++r) {
                float v = acc[mt][nt][r] + bj;
                if (RELU) v = fmaxf(v, 0.f);
                if (Cf) Cf[(size_t)(ib + r) * N + j] = v;
                if (Ch) {
                    ushort_t h = f2bf(v);
                    Ch[(size_t)(ib + r) * N + j] = h;
                    Cl[(size_t)(ib + r) * N + j] = f2bf(v - bf2f(h));
                }
            }
        }
    }
}

// ---------------- batched bf16x3 MFMA QK^T (swizzled, fast exp) ----------------
struct QArgs {
    const ushort_t* qh[3]; const ushort_t* ql[3];
    const ushort_t* kh[3]; const ushort_t* kl[3];
    float* ept[3]; float* rs[3];
};

__global__ __launch_bounds__(256)
void qk_mfma_k(QArgs a, float scale)
{
    __shared__ ushort_t SA[2][128 * 32];
    __shared__ ushort_t SB[2][128 * 32];

    const int z = blockIdx.z;
    const int t = threadIdx.x;
    const int wave = t >> 6, lane = t & 63;
    const int wi = wave & 1, wj = wave >> 1;
    const int i0w = blockIdx.x * 128 + wi * 64;
    const int j0w = blockIdx.y * 128 + wj * 64;
    const int lrow = lane & 15, lquad = lane >> 4;

    const ushort_t* src = (wave == 0) ? a.qh[z] : (wave == 1) ? a.ql[z]
                        : (wave == 2) ? a.kh[z] : a.kl[z];
    ushort_t* dst = (wave == 0) ? &SA[0][0] : (wave == 1) ? &SA[1][0]
                  : (wave == 2) ? &SB[0][0] : &SB[1][0];
    const int rbase = (wave < 2) ? blockIdx.x * 128 : blockIdx.y * 128;
    const int sr = lane >> 2, sq = lane & 3;
    const int gsq = sq ^ ((sr >> 1) & 3);

    float4v acc[4][4] = {};

    for (int k0 = 0; k0 < CC; k0 += 32) {
        #pragma unroll
        for (int it = 0; it < 8; ++it) {
            const ushort_t* g = src + (size_t)(rbase + it * 16 + sr) * CC + k0 + gsq * 8;
            __builtin_amdgcn_global_load_lds(
                (const __attribute__((address_space(1))) void*)g,
                (__attribute__((address_space(3))) void*)(dst + it * 512),
                16, 0, 0);
        }
        __syncthreads();

        short8 Ah[4], Al[4], Bh[4], Bl[4];
        #pragma unroll
        for (int mt = 0; mt < 4; ++mt) {
            int ra = wi * 64 + mt * 16 + lrow;
            int ca = (lquad ^ ((ra >> 1) & 3)) * 8;
            Ah[mt] = *(const short8*)&SA[0][ra * 32 + ca];
            Al[mt] = *(const short8*)&SA[1][ra * 32 + ca];
        }
        #pragma unroll
        for (int nt = 0; nt < 4; ++nt) {
            int rb = wj * 64 + nt * 16 + lrow;
            int cb = (lquad ^ ((rb >> 1) & 3)) * 8;
            Bh[nt] = *(const short8*)&SB[0][rb * 32 + cb];
            Bl[nt] = *(const short8*)&SB[1][rb * 32 + cb];
        }
        #pragma unroll
        for (int mt = 0; mt < 4; ++mt)
            #pragma unroll
            for (int nt = 0; nt < 4; ++nt) {
                acc[mt][nt] = __builtin_amdgcn_mfma_f32_16x16x32_bf16(Ah[mt], Bh[nt], acc[mt][nt], 0, 0, 0);
                acc[mt][nt] = __builtin_amdgcn_mfma_f32_16x16x32_bf16(Ah[mt], Bl[nt], acc[mt][nt], 0, 0, 0);
                acc[mt][nt] = __builtin_amdgcn_mfma_f32_16x16x32_bf16(Al[mt], Bh[nt], acc[mt][nt], 0, 0, 0);
            }
        __syncthreads();
    }

    float* ept = a.ept[z];
    float* rowsum = a.rs[z];
    #pragma unroll
    for (int mt = 0; mt < 4; ++mt) {
        const int ib = i0w + mt * 16 + lquad * 4;
        float part[4] = {0.f, 0.f, 0.f, 0.f};
        #pragma unroll
        for (int nt = 0; nt < 4; ++nt) {
            const int j = j0w + nt * 16 + lrow;
            float e0 = fexp(acc[mt][nt][0] * scale);
            float e1 = fexp(acc[mt][nt][1] * scale);
            float e2 = fexp(acc[mt][nt][2] * scale);
            float e3 = fexp(acc[mt][nt][3] * scale);
            part[0] += e0; part[1] += e1; part[2] += e2; part[3] += e3;
            if (ept)
                *(float4*)&ept[(size_t)j * NN + ib] = make_float4(e0, e1, e2, e3);
        }
        #pragma unroll
        for (int r = 0; r < 4; ++r) {
            float p = part[r];
            p += __shfl_xor(p, 1, 64);
            p += __shfl_xor(p, 2, 64);
            p += __shfl_xor(p, 4, 64);
            p += __shfl_xor(p, 8, 64);
            if (lrow == 0) atomicAdd(&rowsum[ib + r], p);
        }
    }
}

// ---------------- in-place row-sum reciprocal scaling ----------------
__global__ void invrows_k(float* __restrict__ lp, float* __restrict__ ls,
                          const float* agp, const float* bgp)
{
    int i = blockIdx.x * 256 + threadIdx.x;
    lp[i] = (*agp) / lp[i];
    ls[i] = (*bgp) / ls[i];
}

// ---------------- fused GAT vectors: w = gw @ a  (6 of them) ----------------
__global__ __launch_bounds__(256)
void gatvec_k(const float* g0, const float* g1, const float* g2,
              const float* v0, const float* v1, const float* v2,
              const float* v3, const float* v4, const float* v5,
              float* __restrict__ wsd)
{
    int b = blockIdx.x;
    const float* gw = (b < 2) ? g0 : (b < 4) ? g1 : g2;
    const float* av = (b == 0) ? v0 : (b == 1) ? v1 : (b == 2) ? v2
                    : (b == 3) ? v3 : (b == 4) ? v4 : v5;
    int tdx = threadIdx.x;
    float s = 0.f;
    for (int c = 0; c < CC; ++c) s += gw[(size_t)tdx * CC + c] * av[c];
    wsd[b * 256 + tdx] = s;
}

// ---------------- per-node GAT logit halves ----------------
__global__ __launch_bounds__(256)
void hshd_k(const float* __restrict__ Xp, const float* __restrict__ Xs,
            const float* __restrict__ Xa, const float* __restrict__ wsd,
            float* __restrict__ hs, float* __restrict__ hd)
{
    int b = blockIdx.y, row = blockIdx.x, t = threadIdx.x;
    const float* X = (b == 0) ? Xp : (b == 1) ? Xs : Xa;
    float x = X[(size_t)row * CC + t];
    float p1 = x * wsd[b * 512 + t];
    float p2 = x * wsd[b * 512 + 256 + t];
    for (int off = 32; off; off >>= 1) {
        p1 += __shfl_down(p1, off, 64);
        p2 += __shfl_down(p2, off, 64);
    }
    __shared__ float s1[4], s2[4];
    if ((t & 63) == 0) { s1[t >> 6] = p1; s2[t >> 6] = p2; }
    __syncthreads();
    if (t == 0) {
        hs[b * NN + row] = s1[0] + s1[1] + s1[2] + s1[3];
        hd[b * NN + row] = s2[0] + s2[1] + s2[2] + s2[3];
    }
}

// ---------------- fused edge pass: wexp + adjacency bitmap + degree ----------------
__global__ __launch_bounds__(256)
void edge_k(const int* __restrict__ ei, const float* __restrict__ hs,
            const float* __restrict__ hd, float* __restrict__ wexp,
            unsigned* __restrict__ bits, int* __restrict__ cnt)
{
    int e = blockIdx.x * 256 + threadIdx.x;
    int s = ei[e], d = ei[EE + e];
    #pragma unroll
    for (int b = 0; b < 3; ++b) {
        float l = hs[b * NN + s] + hd[b * NN + d];
        l = (l > 0.f) ? l : 0.2f * l;
        wexp[(size_t)b * EE + e] = fexp(l);
    }
    size_t lin = (size_t)d * NN + s;
    atomicOr(&bits[lin >> 5], 1u << (lin & 31));
    atomicAdd(&cnt[d], 1);
}

__global__ void gcount_k(const int* __restrict__ tki, int* __restrict__ cnt)
{
    int p = blockIdx.x * 256 + threadIdx.x;
    atomicAdd(&cnt[tki[p]], 1);
}

__global__ __launch_bounds__(256)
void prefix_k(const int* __restrict__ cnt, int* __restrict__ off, int* __restrict__ cur)
{
    __shared__ int part[257];
    int t = threadIdx.x;
    int loc[16]; int s = 0;
    #pragma unroll
    for (int u = 0; u < 16; ++u) { loc[u] = s; s += cnt[t * 16 + u]; }
    part[t + 1] = s;
    if (t == 0) part[0] = 0;
    __syncthreads();
    if (t == 0) for (int i = 1; i <= 256; ++i) part[i] += part[i - 1];
    __syncthreads();
    int b = part[t];
    #pragma unroll
    for (int u = 0; u < 16; ++u) { off[t * 16 + u] = b + loc[u]; cur[t * 16 + u] = b + loc[u]; }
    if (t == 255) off[4096] = part[256];
}

__global__ void efill_k(const int* __restrict__ ei, int* __restrict__ cur,
                        int* __restrict__ lst)
{
    int e = blockIdx.x * 256 + threadIdx.x;
    int p = atomicAdd(&cur[ei[EE + e]], 1);
    lst[p] = e;
}

__global__ void gfill_k(const int* __restrict__ tki, int* __restrict__ cur,
                        int* __restrict__ lst)
{
    int p = blockIdx.x * 256 + threadIdx.x;
    int q = atomicAdd(&cur[tki[p]], 1);
    lst[q] = p;
}

// ---------------- per-column top-32: wave-private selection, EXACT fp32 keys ----------------
// key = raw fp32 bits (all values >= 0 -> uint compare is exact value order).
// Winner lane reports index + removes exactly one copy; 4-way merge breaks
// value ties by lower index (matches jax.lax.top_k).
__global__ __launch_bounds__(256)
void topk_k(const float* __restrict__ EPT, const float* __restrict__ EST,
            const float* __restrict__ ivp, const float* __restrict__ ivs,
            const unsigned* __restrict__ adjbits,
            int* __restrict__ tki, float* __restrict__ tkv)
{
    __shared__ unsigned lv[4][KT];
    __shared__ int      li[4][KT];
    const int j = blockIdx.x, t = threadIdx.x;
    const int w = t >> 6, lane = t & 63;
    const size_t base = (size_t)j * NN;

    unsigned keys[16], kmax = 0;
    #pragma unroll
    for (int u = 0; u < 16; ++u) {
        int i = w * 1024 + u * 64 + lane;
        float v = EPT[base + i] * ivp[i] + EST[base + i] * ivs[i];
        if ((adjbits[(base + i) >> 5] >> (i & 31)) & 1u) v = 0.f;
        union { float f; unsigned u32; } cv; cv.f = v;
        keys[u] = cv.u32;
        kmax = keys[u] > kmax ? keys[u] : kmax;
    }

    for (int r = 0; r < KT; ++r) {
        unsigned k = kmax;
        #pragma unroll
        for (int off = 1; off < 64; off <<= 1) {
            unsigned o = __shfl_xor(k, off, 64);
            k = o > k ? o : k;
        }
        if (lane == 0) { lv[w][r] = k; li[w][r] = w * 1024; }   // default (k==0 case)
        if (kmax == k && k != 0) {    // winner lane(s) — exact-bit tie across lanes ~impossible
            bool done = false;
            #pragma unroll
            for (int u = 0; u < 16; ++u) {
                if (!done && keys[u] == k) {
                    li[w][r] = w * 1024 + u * 64 + lane;
                    keys[u] = 0;
                    done = true;
                }
            }
            kmax = 0;
            #pragma unroll
            for (int u = 0; u < 16; ++u) kmax = keys[u] > kmax ? keys[u] : kmax;
        }
    }
    __syncthreads();

    // 4-way merge (thread 0); ties by lower index = reference order
    if (t == 0) {
        unsigned hv[4] = {lv[0][0], lv[1][0], lv[2][0], lv[3][0]};
        int      hi_[4] = {li[0][0], li[1][0], li[2][0], li[3][0]};
        int      pp[4] = {0, 0, 0, 0};
        for (int r = 0; r < KT; ++r) {
            int best = 0;
            #pragma unroll
            for (int wsel = 1; wsel < 4; ++wsel)
                if (hv[wsel] > hv[best] || (hv[wsel] == hv[best] && hi_[wsel] < hi_[best]))
                    best = wsel;
            union { unsigned u32; float f; } cv; cv.u32 = hv[best];
            tkv[j * KT + r] = cv.f;
            tki[j * KT + r] = hi_[best];
            int p = ++pp[best];
            hv[best]  = (p < KT) ? lv[best][p] : 0u;
            hi_[best] = (p < KT) ? li[best][p] : 0x7FFFFFFF;
        }
    }
}

// ---------------- aw at sparse positions + column normalize ----------------
__global__ __launch_bounds__(256)
void awcol_k(const ushort_t* __restrict__ qh, const ushort_t* __restrict__ ql,
             const ushort_t* __restrict__ kh, const ushort_t* __restrict__ kl,
             const float* __restrict__ La, const int* __restrict__ tki,
             const float* __restrict__ tkv,
             const float* agp, const float* bgp, const float* cgp,
             float* __restrict__ gn)
{
    __shared__ float kj[CC];
    __shared__ float gv[KT];
    __shared__ float cs_sh;
    int j = blockIdx.x, t = threadIdx.x;
    kj[t] = bf2f(kh[(size_t)j * CC + t]) + bf2f(kl[(size_t)j * CC + t]);
    __syncthreads();
    float hg = 0.5f * (*agp) + 0.5f * (*bgp), cg = *cgp;
    int wv = t >> 6, ln = t & 63;
    for (int k = wv; k < KT; k += 4) {
        int i = tki[j * KT + k];
        float p = 0.f;
        #pragma unroll
        for (int u = 0; u < 4; ++u) {
            int c = ln + u * 64;
            float q = bf2f(qh[(size_t)i * CC + c]) + bf2f(ql[(size_t)i * CC + c]);
            p += q * kj[c];
        }
        for (int off = 32; off; off >>= 1) p += __shfl_down(p, off, 64);
        if (ln == 0) {
            float aw = fexp(p * 0.0625f) / La[i];
            gv[k] = hg * tkv[j * KT + k] + cg * aw;
        }
    }
    __syncthreads();
    if (t == 0) { float cs = 0.f; for (int k = 0; k < KT; ++k) cs += gv[k]; cs_sh = cs; }
    __syncthreads();
    if (t < KT) gn[j * KT + t] = gv[t] / cs_sh;
}

// ---------------- unrolled broadcast gather core ----------------
__device__ __forceinline__ void gather_accum(const float* __restrict__ aem, int ln, int n,
                                             float la, int s, float4& acc)
{
    int u = 0;
    for (; u + 4 <= n; u += 4) {
        float l0 = __shfl(la, u, 64),     l1 = __shfl(la, u + 1, 64);
        float l2 = __shfl(la, u + 2, 64), l3 = __shfl(la, u + 3, 64);
        int   s0 = __shfl(s, u, 64),      s1 = __shfl(s, u + 1, 64);
        int   s2 = __shfl(s, u + 2, 64),  s3 = __shfl(s, u + 3, 64);
        const float4 v0 = *(const float4*)&aem[(size_t)s0 * CC + ln * 4];
        const float4 v1 = *(const float4*)&aem[(size_t)s1 * CC + ln * 4];
        const float4 v2 = *(const float4*)&aem[(size_t)s2 * CC + ln * 4];
        const float4 v3 = *(const float4*)&aem[(size_t)s3 * CC + ln * 4];
        acc.x += l0 * v0.x + l1 * v1.x + l2 * v2.x + l3 * v3.x;
        acc.y += l0 * v0.y + l1 * v1.y + l2 * v2.y + l3 * v3.y;
        acc.z += l0 * v0.z + l1 * v1.z + l2 * v2.z + l3 * v3.z;
        acc.w += l0 * v0.w + l1 * v1.w + l2 * v2.w + l3 * v3.w;
    }
    for (; u < n; ++u) {
        float lu = __shfl(la, u, 64);
        int   su = __shfl(s, u, 64);
        const float4 v = *(const float4*)&aem[(size_t)su * CC + ln * 4];
        acc.x += lu * v.x; acc.y += lu * v.y;
        acc.z += lu * v.z; acc.w += lu * v.w;
    }
}

// ---------------- merged local+global gather -> split bf16 into K-concat OUTC ----------------
__global__ __launch_bounds__(256)
void gather_k(const int* __restrict__ ei, const int* __restrict__ eoff,
              const int* __restrict__ elst, const float* __restrict__ wexp,
              const int* __restrict__ goff, const int* __restrict__ glst,
              const float* __restrict__ gn, const float* __restrict__ aem,
              const float* alp, const float* blp, const float* clp,
              ushort_t* __restrict__ outch, ushort_t* __restrict__ outcl)
{
    int wv = threadIdx.x >> 6, ln = threadIdx.x & 63;
    float4 acc = {0.f, 0.f, 0.f, 0.f};

    if (blockIdx.x < NN / 4) {                   // ---- local branch ----
        int d = blockIdx.x * 4 + wv;
        int beg = eoff[d], end = eoff[d + 1];

        float s1 = 0.f, s2 = 0.f, s3 = 0.f;      // softmax denominators (wave reduce)
        for (int c = beg + ln; c < end; c += 64) {
            int e = elst[c];
            s1 += wexp[e];
            s2 += wexp[EE + e];
            s3 += wexp[2 * (size_t)EE + e];
        }
        #pragma unroll
        for (int off = 1; off < 64; off <<= 1) {
            s1 += __shfl_xor(s1, off, 64);
            s2 += __shfl_xor(s2, off, 64);
            s3 += __shfl_xor(s3, off, 64);
        }
        float i0 = (*alp) / s1, i1 = (*blp) / s2, i2 = (*clp) / s3;

        for (int c = beg; c < end; c += 64) {
            int n = min(64, end - c);
            int s = 0; float la = 0.f;
            if (ln < n) {
                int e = elst[c + ln];
                s = ei[e];
                la = i0 * wexp[e] + i1 * wexp[EE + e] + i2 * wexp[2 * (size_t)EE + e];
            }
            gather_accum(aem, ln, n, la, s, acc);
        }
        float inv = 1.f / fmaxf((float)(end - beg), 1.f);
        acc.x *= inv; acc.y *= inv; acc.z *= inv; acc.w *= inv;

        ushort_t h0 = f2bf(acc.x), h1 = f2bf(acc.y), h2 = f2bf(acc.z), h3 = f2bf(acc.w);
        uint2 hw, lw;
        hw.x = (unsigned)h0 | ((unsigned)h1 << 16); hw.y = (unsigned)h2 | ((unsigned)h3 << 16);
        lw.x = (unsigned)f2bf(acc.x - bf2f(h0)) | ((unsigned)f2bf(acc.y - bf2f(h1)) << 16);
        lw.y = (unsigned)f2bf(acc.z - bf2f(h2)) | ((unsigned)f2bf(acc.w - bf2f(h3)) << 16);
        *(uint2*)&outch[(size_t)d * 512 + ln * 4] = hw;
        *(uint2*)&outcl[(size_t)d * 512 + ln * 4] = lw;
    } else {                                     // ---- global branch ----
        int i = (blockIdx.x - NN / 4) * 4 + wv;
        int beg = goff[i], end = goff[i + 1];
        for (int c = beg; c < end; c += 64) {
            int n = min(64, end - c);
            int jcol = 0; float g = 0.f;
            if (ln < n) {
                int p = glst[c + ln];
                jcol = p >> 5;
                g = gn[p];
            }
            gather_accum(aem, ln, n, g, jcol, acc);
        }
        ushort_t h0 = f2bf(acc.x), h1 = f2bf(acc.y), h2 = f2bf(acc.z), h3 = f2bf(acc.w);
        uint2 hw, lw;
        hw.x = (unsigned)h0 | ((unsigned)h1 << 16); hw.y = (unsigned)h2 | ((unsigned)h3 << 16);
        lw.x = (unsigned)f2bf(acc.x - bf2f(h0)) | ((unsigned)f2bf(acc.y - bf2f(h1)) << 16);
        lw.y = (unsigned)f2bf(acc.z - bf2f(h2)) | ((unsigned)f2bf(acc.w - bf2f(h3)) << 16);
        *(uint2*)&outch[(size_t)i * 512 + 256 + ln * 4] = hw;
        *(uint2*)&outcl[(size_t)i * 512 + 256 + ln * 4] = lw;
    }
}

__global__ void diag_k(float* out, float v) { out[0] = v; }

// ---------------- host ----------------
extern "C" void kernel_launch(void* const* d_in, const int* in_sizes, int n_in,
                              void* d_out, int out_size, void* d_ws, size_t ws_size,
                              hipStream_t stream)
{
    (void)in_sizes; (void)n_in; (void)out_size;

    if (ws_size < WS_FLOATS * sizeof(float)) {
        diag_k<<<1, 1, 0, stream>>>((float*)d_out, (float)(ws_size >> 20));
        return;
    }

    float* W = (float*)d_ws;
    float* EPT = W + OFF_EPT;  float* EST = W + OFF_EST;
    float* LP = W + OFF_LP;    float* LS = W + OFF_LS;   float* LA = W + OFF_LA;
    int* ECNT = (int*)(W + OFF_ECNT);
    int* GCNT = (int*)(W + OFF_GCNT);
    unsigned* ADJ = (unsigned*)(W + OFF_ADJ);
    float* XM = W + OFF_XM;
    ushort_t* QKS = (ushort_t*)(W + OFF_QK);
    float* WEXP = W + OFF_WEXP;
    float* HS = W + OFF_HS;    float* HD = W + OFF_HD;   float* WSD = W + OFF_WSD;
    int*   TKI = (int*)(W + OFF_TKI);
    float* TKV = W + OFF_TKV;  float* GN = W + OFF_GN;
    int* EOFF = (int*)(W + OFF_EOFF); int* ECUR = (int*)(W + OFF_ECUR);
    int* ELST = (int*)(W + OFF_ELST);
    int* GOFF = (int*)(W + OFF_GOFF); int* GCUR = (int*)(W + OFF_GCUR);
    int* GLST = (int*)(W + OFF_GLST);

    ushort_t* PRO = (ushort_t*)EPT;            // prologue scratch (dead until qk writes EPT)
    ushort_t* EPI = (ushort_t*)EST;            // epilogue scratch (dead after topk)
    ushort_t* WLT = (ushort_t*)(W + OFF_WLT);  // combined final weight (survives qk)

    ushort_t* XINH = PRO + SH_XINH; ushort_t* XINL = PRO + SH_XINL;
    ushort_t* HIDH = PRO + SH_HIDH; ushort_t* HIDL = PRO + SH_HIDL;
    ushort_t* XMH  = PRO + SH_XMH;  ushort_t* XML  = PRO + SH_XML;

    auto W1T = [&](int b, int hl) { return PRO + SH_WT + (size_t)b * WT_BR + hl * 131072; };
    auto W2T = [&](int b, int hl) { return PRO + SH_WT + (size_t)b * WT_BR + 262144 + hl * 131072; };
    auto WQT = [&](int b, int hl) { return PRO + SH_WT + (size_t)b * WT_BR + 524288 + hl * 65536; };
    auto WKT = [&](int b, int hl) { return PRO + SH_WT + (size_t)b * WT_BR + 655360 + hl * 65536; };
    ushort_t* WCT_H = WLT;            // combined [wloc;wglb]^T hi: [256 n][512 k]
    ushort_t* WCT_L = WLT + 131072;
    ushort_t* OUTCH = EPI;            // [4096][512] hi
    ushort_t* OUTCL = EPI + 2097152;  // [4096][512] lo

    auto QHp = [&](int b) { return QKS + (size_t)(b * 4 + 0) * 1048576; };
    auto QLp = [&](int b) { return QKS + (size_t)(b * 4 + 1) * 1048576; };
    auto KHp = [&](int b) { return QKS + (size_t)(b * 4 + 2) * 1048576; };
    auto KLp = [&](int b) { return QKS + (size_t)(b * 4 + 3) * 1048576; };

    // branch order [pe, se, ae] to match (a_*, b_*, c_*) coefficient order
    const float* Xin[3] = {(const float*)d_in[1], (const float*)d_in[2], (const float*)d_in[0]};
    const int base_idx[3] = {14, 25, 3};
    const float *w1[3], *b1[3], *w2[3], *b2[3], *gw[3], *asv[3], *adv[3], *wq[3], *bq[3], *wk[3], *bk[3];
    for (int b = 0; b < 3; ++b) {
        int o = base_idx[b];
        w1[b] = (const float*)d_in[o + 0]; b1[b] = (const float*)d_in[o + 1];
        w2[b] = (const float*)d_in[o + 2]; b2[b] = (const float*)d_in[o + 3];
        gw[b] = (const float*)d_in[o + 4]; asv[b] = (const float*)d_in[o + 5];
        adv[b] = (const float*)d_in[o + 6];
        wq[b] = (const float*)d_in[o + 7]; bq[b] = (const float*)d_in[o + 8];
        wk[b] = (const float*)d_in[o + 9]; bk[b] = (const float*)d_in[o + 10];
    }
    const float* al = (const float*)d_in[36]; const float* bl = (const float*)d_in[37];
    const float* cl = (const float*)d_in[38];
    const float* ag = (const float*)d_in[39]; const float* bg = (const float*)d_in[40];
    const float* cg = (const float*)d_in[41];
    const float* wloc = (const float*)d_in[42];
    const float* wglb = (const float*)d_in[43];
    const int* ei = (const int*)d_in[44];

    dim3 blk(256);

    // 0. zero accumulators
    hipMemsetAsync(LP, 0, (ZERO_END - OFF_LP) * sizeof(float), stream);

    // 0b. all weight transposes+splits in one batched launch (z = 14)
    {
        TArgs a{};
        for (int b = 0; b < 3; ++b) {
            a.s[b] = w1[b]; a.h[b] = W1T(b, 0); a.l[b] = W1T(b, 1);
            a.nshift[b] = 9; a.total[b] = 131072; a.kstride[b] = 256; a.koff[b] = 0;
            a.s[3 + b] = w2[b]; a.h[3 + b] = W2T(b, 0); a.l[3 + b] = W2T(b, 1);
            a.nshift[3 + b] = 8; a.total[3 + b] = 131072; a.kstride[3 + b] = 512; a.koff[3 + b] = 0;
            a.s[6 + b] = wq[b]; a.h[6 + b] = WQT(b, 0); a.l[6 + b] = WQT(b, 1);
            a.nshift[6 + b] = 8; a.total[6 + b] = 65536; a.kstride[6 + b] = 256; a.koff[6 + b] = 0;
            a.s[9 + b] = wk[b]; a.h[9 + b] = WKT(b, 0); a.l[9 + b] = WKT(b, 1);
            a.nshift[9 + b] = 8; a.total[9 + b] = 65536; a.kstride[9 + b] = 256; a.koff[9 + b] = 0;
        }
        a.s[12] = wloc; a.h[12] = WCT_H; a.l[12] = WCT_L;
        a.nshift[12] = 8; a.total[12] = 65536; a.kstride[12] = 512; a.koff[12] = 0;
        a.s[13] = wglb; a.h[13] = WCT_H; a.l[13] = WCT_L;
        a.nshift[13] = 8; a.total[13] = 65536; a.kstride[13] = 512; a.koff[13] = 256;
        wtrans_k<<<dim3(512, 1, 14), blk, 0, stream>>>(a);
    }

    // 0c. split inputs pe/se/ae -> hi/lo bf16
    split3_k<<<dim3(1024, 1, 3), blk, 0, stream>>>(Xin[0], Xin[1], Xin[2], XINH, XINL, 1048576);

    // 1. MLP1 batched (z=3): HID[b] = relu(X@w1+b1) -> split
    {
        MArgs a{};
        for (int b = 0; b < 3; ++b) {
            a.Ah[b] = XINH + (size_t)b * 1048576; a.Al[b] = XINL + (size_t)b * 1048576;
            a.Bh[b] = W1T(b, 0); a.Bl[b] = W1T(b, 1); a.bias[b] = b1[b];
            a.Cf[b] = nullptr;
            a.Ch[b] = HIDH + (size_t)b * 2097152; a.Cl[b] = HIDL + (size_t)b * 2097152;
        }
        mgemm_k<1><<<dim3(32, 8, 3), blk, 0, stream>>>(a, 512, 256);
    }
    // 1b. MLP2 batched (z=3): XM[b] = HID@w2+b2 -> fp32 + split
    {
        MArgs a{};
        for (int b = 0; b < 3; ++b) {
            a.Ah[b] = HIDH + (size_t)b * 2097152; a.Al[b] = HIDL + (size_t)b * 2097152;
            a.Bh[b] = W2T(b, 0); a.Bl[b] = W2T(b, 1); a.bias[b] = b2[b];
            a.Cf[b] = XM + (size_t)b * 1048576;
            a.Ch[b] = XMH + (size_t)b * 1048576; a.Cl[b] = XML + (size_t)b * 1048576;
        }
        mgemm_k<0><<<dim3(32, 4, 3), blk, 0, stream>>>(a, 256, 512);
    }

    // 2. GAT vecs + per-node halves + fused edge pass (wexp/adj/degree)
    gatvec_k<<<6, blk, 0, stream>>>(gw[0], gw[1], gw[2],
                                    asv[0], adv[0], asv[1], adv[1], asv[2], adv[2], WSD);
    hshd_k<<<dim3(NN, 3), blk, 0, stream>>>(XM, XM + 1048576, XM + 2 * 1048576, WSD, HS, HD);
    edge_k<<<EE / 256, blk, 0, stream>>>(ei, HS, HD, WEXP, ADJ, ECNT);

    // 2b. edge CSR by dst
    prefix_k<<<1, blk, 0, stream>>>(ECNT, EOFF, ECUR);
    efill_k<<<EE / 256, blk, 0, stream>>>(ei, ECUR, ELST);

    // 3. q/k projections batched (z=6) -> hi/lo bf16
    {
        MArgs a{};
        for (int b = 0; b < 3; ++b) {
            a.Ah[b] = XMH + (size_t)b * 1048576; a.Al[b] = XML + (size_t)b * 1048576;
            a.Bh[b] = WQT(b, 0); a.Bl[b] = WQT(b, 1); a.bias[b] = bq[b];
            a.Cf[b] = nullptr; a.Ch[b] = QHp(b); a.Cl[b] = QLp(b);
            a.Ah[3 + b] = a.Ah[b]; a.Al[3 + b] = a.Al[b];
            a.Bh[3 + b] = WKT(b, 0); a.Bl[3 + b] = WKT(b, 1); a.bias[3 + b] = bk[b];
            a.Cf[3 + b] = nullptr; a.Ch[3 + b] = KHp(b); a.Cl[3 + b] = KLp(b);
        }
        mgemm_k<0><<<dim3(32, 4, 6), blk, 0, stream>>>(a, 256, 256);
    }

    // 4. QK^T batched (z=3); ae branch rowsum-only
    {
        QArgs a{};
        for (int b = 0; b < 3; ++b) {
            a.qh[b] = QHp(b); a.ql[b] = QLp(b); a.kh[b] = KHp(b); a.kl[b] = KLp(b);
        }
        a.ept[0] = EPT; a.rs[0] = LP;
        a.ept[1] = EST; a.rs[1] = LS;
        a.ept[2] = nullptr; a.rs[2] = LA;
        qk_mfma_k<<<dim3(32, 32, 3), blk, 0, stream>>>(a, 0.0625f);
    }

    // 4b. Lp <- ag/Lp, Ls <- bg/Ls
    invrows_k<<<16, blk, 0, stream>>>(LP, LS, ag, bg);

    // 5. per-column top-32 of adj-masked sample_attn (exact fp32 order)
    topk_k<<<NN, blk, 0, stream>>>(EPT, EST, LP, LS, ADJ, TKI, TKV);

    // 5b. global CSR by destination row i
    gcount_k<<<(NN * KT) / 256, blk, 0, stream>>>(TKI, GCNT);
    prefix_k<<<1, blk, 0, stream>>>(GCNT, GOFF, GCUR);
    gfill_k<<<(NN * KT) / 256, blk, 0, stream>>>(TKI, GCUR, GLST);

    // 6. sparse aw + column-normalized g values
    awcol_k<<<NN, blk, 0, stream>>>(QHp(2), QLp(2), KHp(2), KLp(2), LA,
                                    TKI, TKV, ag, bg, cg, GN);

    // 7/8. merged gathers write split bf16 directly into K-concat [OUTL|OUTG]
    gather_k<<<NN / 2, blk, 0, stream>>>(ei, EOFF, ELST, WEXP, GOFF, GLST, GN,
                                         XM + 2 * 1048576, al, bl, cl, OUTCH, OUTCL);

    // 9. out = [OUTL|OUTG] @ [wloc;wglb]  (single K=512 MFMA GEMM)
    {
        MArgs a{};
        a.Ah[0] = OUTCH; a.Al[0] = OUTCL;
        a.Bh[0] = WCT_H; a.Bl[0] = WCT_L; a.bias[0] = nullptr;
        a.Cf[0] = (float*)d_out; a.Ch[0] = nullptr; a.Cl[0] = nullptr;
        mgemm_k<0><<<dim3(32, 4, 1), blk, 0, stream>>>(a, 256, 512);
    }
}

// Round 11
// 554.070 us; speedup vs baseline: 1.1121x; 1.1121x over previous
//
#include <hip/hip_runtime.h>

#define NN 4096
#define CC 256
#define EE 131072
#define KT 32

typedef unsigned short ushort_t;
typedef __attribute__((ext_vector_type(8))) short short8;   // bf16x8 (4 VGPRs)
typedef __attribute__((ext_vector_type(4))) float float4v;  // fp32x4 acc

__device__ __forceinline__ ushort_t f2bf(float x) {
    union { float f; unsigned u; } a; a.f = x;
    unsigned r = (a.u + 0x7FFF + ((a.u >> 16) & 1)) >> 16;   // RNE
    return (ushort_t)r;
}
__device__ __forceinline__ float bf2f(ushort_t b) {
    union { float f; unsigned u; } a; a.u = ((unsigned)b) << 16;
    return a.f;
}
// fast exp: v_exp_f32 is exp2 (~1 ulp); inputs bounded |x| < ~15 here
__device__ __forceinline__ float fexp(float x) {
#if __has_builtin(__builtin_amdgcn_exp2f)
    return __builtin_amdgcn_exp2f(x * 1.4426950408889634f);
#else
    return exp2f(x * 1.4426950408889634f);
#endif
}

// ---------------- workspace layout (float slots) ----------------
constexpr size_t OFF_EPT  = 0;                         // exp(pe logits)^T [j][i] 4096x4096
constexpr size_t OFF_EST  = OFF_EPT + 16777216;        // exp(se logits)^T
// --- zero region ---
constexpr size_t OFF_LP   = OFF_EST + 16777216;        // -> ag/Lp after invrows
constexpr size_t OFF_LS   = OFF_LP + 4096;
constexpr size_t OFF_LA   = OFF_LS + 4096;
constexpr size_t OFF_ECNT = OFF_LA + 4096;             // int: in-degree per dst
constexpr size_t OFF_GCNT = OFF_ECNT + 4096;           // int: global-entry count per row i
constexpr size_t OFF_ADJ  = OFF_GCNT + 4096;           // 524288 u32 adjacency bitmap [dst][src]
constexpr size_t ZERO_END = OFF_ADJ + 524288;
// --- non-zeroed ---
constexpr size_t OFF_XM   = ZERO_END;                  // pe_m, se_m, ae_m fp32 (3 x 4096x256)
constexpr size_t OFF_QK   = OFF_XM + 3*1048576;        // 12 bf16 arrays: (qh,ql,kh,kl) x 3 branch
constexpr size_t OFF_WEXP = OFF_QK + 6*1048576;        // 3*E exp(edge logits)
constexpr size_t OFF_HS   = OFF_WEXP + 3*131072;       // 3*4096
constexpr size_t OFF_HD   = OFF_HS + 12288;
constexpr size_t OFF_WSD  = OFF_HD + 12288;            // 6*256 fused gat vecs
constexpr size_t OFF_TKI  = OFF_WSD + 1536;            // topk indices (int) 4096*32
constexpr size_t OFF_TKV  = OFF_TKI + 131072;          // topk sample values
constexpr size_t OFF_GN   = OFF_TKV + 131072;          // normalized g values
constexpr size_t OFF_EOFF = OFF_GN + 131072;           // int 4097 csr offsets (edges by dst)
constexpr size_t OFF_ECUR = OFF_EOFF + 4097;           // int 4096 fill cursors
constexpr size_t OFF_ELST = OFF_ECUR + 4096;           // int E edge ids
constexpr size_t OFF_GOFF = OFF_ELST + 131072;         // int 4097
constexpr size_t OFF_GCUR = OFF_GOFF + 4097;           // int 4096
constexpr size_t OFF_GLST = OFF_GCUR + 4096;           // int N*K entry ids
constexpr size_t OFF_WLT  = OFF_GLST + 131072;         // combined [wloc;wglb]^T hi+lo (262144 shorts)
constexpr size_t WS_FLOATS = OFF_WLT + 131072;         // ~189 MiB

// -- transient bf16 sub-layouts (short offsets) --
constexpr size_t SH_XINH = 0;                          // 3 x 1M
constexpr size_t SH_XINL = 3145728;
constexpr size_t SH_HIDH = 6291456;                    // 3 x 2M
constexpr size_t SH_HIDL = 12582912;
constexpr size_t SH_XMH  = 18874368;                   // 3 x 1M
constexpr size_t SH_XML  = 22020096;
constexpr size_t SH_WT   = 25165824;                   // per-branch transposed weights
constexpr size_t WT_BR   = 786432;                     // shorts per branch

// ---------------- batched weight transpose + split ----------------
struct TArgs {
    const float* s[14]; ushort_t* h[14]; ushort_t* l[14];
    int nshift[14]; int total[14]; int kstride[14]; int koff[14];
};

__global__ __launch_bounds__(256)
void wtrans_k(TArgs a)
{
    int z = blockIdx.z;
    int idx = blockIdx.x * 256 + threadIdx.x;
    if (idx >= a.total[z]) return;
    int n = idx & ((1 << a.nshift[z]) - 1);
    int k = idx >> a.nshift[z];
    float v = a.s[z][idx];
    ushort_t hh = f2bf(v);
    size_t o = (size_t)n * a.kstride[z] + a.koff[z] + k;
    a.h[z][o] = hh;
    a.l[z][o] = f2bf(v - bf2f(hh));
}

// ---------------- activation split: h/l bf16 copies ----------------
__global__ __launch_bounds__(256)
void split3_k(const float* s0, const float* s1, const float* s2,
              ushort_t* hb, ushort_t* lb, size_t nper)
{
    int z = blockIdx.z;
    const float* s = (z == 0) ? s0 : (z == 1) ? s1 : s2;
    ushort_t* h = hb + (size_t)z * nper;
    ushort_t* l = lb + (size_t)z * nper;
    size_t i = (size_t)(blockIdx.x * 256 + threadIdx.x) * 4;
    float4 v = *(const float4*)(s + i);
    ushort_t h0 = f2bf(v.x), h1 = f2bf(v.y), h2 = f2bf(v.z), h3 = f2bf(v.w);
    ushort_t l0 = f2bf(v.x - bf2f(h0)), l1 = f2bf(v.y - bf2f(h1));
    ushort_t l2 = f2bf(v.z - bf2f(h2)), l3 = f2bf(v.w - bf2f(h3));
    uint2 hw, lw;
    hw.x = (unsigned)h0 | ((unsigned)h1 << 16); hw.y = (unsigned)h2 | ((unsigned)h3 << 16);
    lw.x = (unsigned)l0 | ((unsigned)l1 << 16); lw.y = (unsigned)l2 | ((unsigned)l3 << 16);
    *(uint2*)(h + i) = hw;
    *(uint2*)(l + i) = lw;
}

// ---------------- batched bf16x3 MFMA GEMM: C[z] = A[z] @ B[z]^T ----------------
// 128x64 tile: wave w computes rows w*32..w*32+31 x all 64 cols.
struct MArgs {
    const ushort_t* Ah[6]; const ushort_t* Al[6];
    const ushort_t* Bh[6]; const ushort_t* Bl[6];
    const float* bias[6];
    float* Cf[6]; ushort_t* Ch[6]; ushort_t* Cl[6];
};

template<int RELU>
__global__ __launch_bounds__(256)
void mgemm_k(MArgs a, int N, int K)
{
    __shared__ ushort_t SA[2][128 * 32];
    __shared__ ushort_t SB[2][64 * 32];

    const int z = blockIdx.z;
    const int t = threadIdx.x, wave = t >> 6, lane = t & 63;
    const int lrow = lane & 15, lquad = lane >> 4;

    const ushort_t* src = (wave == 0) ? a.Ah[z] : (wave == 1) ? a.Al[z]
                        : (wave == 2) ? a.Bh[z] : a.Bl[z];
    ushort_t* dst = (wave == 0) ? &SA[0][0] : (wave == 1) ? &SA[1][0]
                  : (wave == 2) ? &SB[0][0] : &SB[1][0];
    const int rbase = (wave < 2) ? blockIdx.x * 128 : blockIdx.y * 64;
    const int sr = lane >> 2, sq = lane & 3;
    const int gsq = sq ^ ((sr >> 1) & 3);          // staging-side swizzle

    float4v acc[2][4] = {};

    for (int k0 = 0; k0 < K; k0 += 32) {
        if (wave < 2) {
            #pragma unroll
            for (int it = 0; it < 8; ++it) {
                const ushort_t* g = src + (size_t)(rbase + it * 16 + sr) * K + k0 + gsq * 8;
                __builtin_amdgcn_global_load_lds(
                    (const __attribute__((address_space(1))) void*)g,
                    (__attribute__((address_space(3))) void*)(dst + it * 512),
                    16, 0, 0);
            }
        } else {
            #pragma unroll
            for (int it = 0; it < 4; ++it) {
                const ushort_t* g = src + (size_t)(rbase + it * 16 + sr) * K + k0 + gsq * 8;
                __builtin_amdgcn_global_load_lds(
                    (const __attribute__((address_space(1))) void*)g,
                    (__attribute__((address_space(3))) void*)(dst + it * 512),
                    16, 0, 0);
            }
        }
        __syncthreads();

        short8 fAh[2], fAl[2], fBh[4], fBl[4];
        #pragma unroll
        for (int mt = 0; mt < 2; ++mt) {
            int ra = wave * 32 + mt * 16 + lrow;
            int ca = (lquad ^ ((ra >> 1) & 3)) * 8;
            fAh[mt] = *(const short8*)&SA[0][ra * 32 + ca];
            fAl[mt] = *(const short8*)&SA[1][ra * 32 + ca];
        }
        #pragma unroll
        for (int nt = 0; nt < 4; ++nt) {
            int rb = nt * 16 + lrow;
            int cb = (lquad ^ ((rb >> 1) & 3)) * 8;
            fBh[nt] = *(const short8*)&SB[0][rb * 32 + cb];
            fBl[nt] = *(const short8*)&SB[1][rb * 32 + cb];
        }
        #pragma unroll
        for (int mt = 0; mt < 2; ++mt)
            #pragma unroll
            for (int nt = 0; nt < 4; ++nt) {
                acc[mt][nt] = __builtin_amdgcn_mfma_f32_16x16x32_bf16(fAh[mt], fBh[nt], acc[mt][nt], 0, 0, 0);
                acc[mt][nt] = __builtin_amdgcn_mfma_f32_16x16x32_bf16(fAh[mt], fBl[nt], acc[mt][nt], 0, 0, 0);
                acc[mt][nt] = __builtin_amdgcn_mfma_f32_16x16x32_bf16(fAl[mt], fBh[nt], acc[mt][nt], 0, 0, 0);
            }
        __syncthreads();
    }

    const float* bias = a.bias[z];
    float* Cf = a.Cf[z];
    ushort_t* Ch = a.Ch[z]; ushort_t* Cl = a.Cl[z];
    const int i0w = blockIdx.x * 128 + wave * 32, j0w = blockIdx.y * 64;
    #pragma unroll
    for (int mt = 0; mt < 2; ++mt) {
        const int ib = i0w + mt * 16 + lquad * 4;
        #pragma unroll
        for (int nt = 0; nt < 4; ++nt) {
            const int j = j0w + nt * 16 + lrow;
            float bj = bias ? bias[j] : 0.f;
            #pragma unroll
            for (int r = 0; r < 4; ++r) {
                float v = acc[mt][nt][r] + bj;
                if (RELU) v = fmaxf(v, 0.f);
                if (Cf) Cf[(size_t)(ib + r) * N + j] = v;
                if (Ch) {
                    ushort_t h = f2bf(v);
                    Ch[(size_t)(ib + r) * N + j] = h;
                    Cl[(size_t)(ib + r) * N + j] = f2bf(v - bf2f(h));
                }
            }
        }
    }
}

// ---------------- batched bf16x3 MFMA QK^T (swizzled, fast exp) ----------------
struct QArgs {
    const ushort_t* qh[3]; const ushort_t* ql[3];
    const ushort_t* kh[3]; const ushort_t* kl[3];
    float* ept[3]; float* rs[3];
};

__global__ __launch_bounds__(256)
void qk_mfma_k(QArgs a, float scale)
{
    __shared__ ushort_t SA[2][128 * 32];
    __shared__ ushort_t SB[2][128 * 32];

    const int z = blockIdx.z;
    const int t = threadIdx.x;
    const int wave = t >> 6, lane = t & 63;
    const int wi = wave & 1, wj = wave >> 1;
    const int i0w = blockIdx.x * 128 + wi * 64;
    const int j0w = blockIdx.y * 128 + wj * 64;
    const int lrow = lane & 15, lquad = lane >> 4;

    const ushort_t* src = (wave == 0) ? a.qh[z] : (wave == 1) ? a.ql[z]
                        : (wave == 2) ? a.kh[z] : a.kl[z];
    ushort_t* dst = (wave == 0) ? &SA[0][0] : (wave == 1) ? &SA[1][0]
                  : (wave == 2) ? &SB[0][0] : &SB[1][0];
    const int rbase = (wave < 2) ? blockIdx.x * 128 : blockIdx.y * 128;
    const int sr = lane >> 2, sq = lane & 3;
    const int gsq = sq ^ ((sr >> 1) & 3);

    float4v acc[4][4] = {};

    for (int k0 = 0; k0 < CC; k0 += 32) {
        #pragma unroll
        for (int it = 0; it < 8; ++it) {
            const ushort_t* g = src + (size_t)(rbase + it * 16 + sr) * CC + k0 + gsq * 8;
            __builtin_amdgcn_global_load_lds(
                (const __attribute__((address_space(1))) void*)g,
                (__attribute__((address_space(3))) void*)(dst + it * 512),
                16, 0, 0);
        }
        __syncthreads();

        short8 Ah[4], Al[4], Bh[4], Bl[4];
        #pragma unroll
        for (int mt = 0; mt < 4; ++mt) {
            int ra = wi * 64 + mt * 16 + lrow;
            int ca = (lquad ^ ((ra >> 1) & 3)) * 8;
            Ah[mt] = *(const short8*)&SA[0][ra * 32 + ca];
            Al[mt] = *(const short8*)&SA[1][ra * 32 + ca];
        }
        #pragma unroll
        for (int nt = 0; nt < 4; ++nt) {
            int rb = wj * 64 + nt * 16 + lrow;
            int cb = (lquad ^ ((rb >> 1) & 3)) * 8;
            Bh[nt] = *(const short8*)&SB[0][rb * 32 + cb];
            Bl[nt] = *(const short8*)&SB[1][rb * 32 + cb];
        }
        #pragma unroll
        for (int mt = 0; mt < 4; ++mt)
            #pragma unroll
            for (int nt = 0; nt < 4; ++nt) {
                acc[mt][nt] = __builtin_amdgcn_mfma_f32_16x16x32_bf16(Ah[mt], Bh[nt], acc[mt][nt], 0, 0, 0);
                acc[mt][nt] = __builtin_amdgcn_mfma_f32_16x16x32_bf16(Ah[mt], Bl[nt], acc[mt][nt], 0, 0, 0);
                acc[mt][nt] = __builtin_amdgcn_mfma_f32_16x16x32_bf16(Al[mt], Bh[nt], acc[mt][nt], 0, 0, 0);
            }
        __syncthreads();
    }

    float* ept = a.ept[z];
    float* rowsum = a.rs[z];
    #pragma unroll
    for (int mt = 0; mt < 4; ++mt) {
        const int ib = i0w + mt * 16 + lquad * 4;
        float part[4] = {0.f, 0.f, 0.f, 0.f};
        #pragma unroll
        for (int nt = 0; nt < 4; ++nt) {
            const int j = j0w + nt * 16 + lrow;
            float e0 = fexp(acc[mt][nt][0] * scale);
            float e1 = fexp(acc[mt][nt][1] * scale);
            float e2 = fexp(acc[mt][nt][2] * scale);
            float e3 = fexp(acc[mt][nt][3] * scale);
            part[0] += e0; part[1] += e1; part[2] += e2; part[3] += e3;
            if (ept)
                *(float4*)&ept[(size_t)j * NN + ib] = make_float4(e0, e1, e2, e3);
        }
        #pragma unroll
        for (int r = 0; r < 4; ++r) {
            float p = part[r];
            p += __shfl_xor(p, 1, 64);
            p += __shfl_xor(p, 2, 64);
            p += __shfl_xor(p, 4, 64);
            p += __shfl_xor(p, 8, 64);
            if (lrow == 0) atomicAdd(&rowsum[ib + r], p);
        }
    }
}

// ---------------- in-place row-sum reciprocal scaling ----------------
__global__ void invrows_k(float* __restrict__ lp, float* __restrict__ ls,
                          const float* agp, const float* bgp)
{
    int i = blockIdx.x * 256 + threadIdx.x;
    lp[i] = (*agp) / lp[i];
    ls[i] = (*bgp) / ls[i];
}

// ---------------- fused GAT vectors: w = gw @ a  (6 of them) ----------------
__global__ __launch_bounds__(256)
void gatvec_k(const float* g0, const float* g1, const float* g2,
              const float* v0, const float* v1, const float* v2,
              const float* v3, const float* v4, const float* v5,
              float* __restrict__ wsd)
{
    int b = blockIdx.x;
    const float* gw = (b < 2) ? g0 : (b < 4) ? g1 : g2;
    const float* av = (b == 0) ? v0 : (b == 1) ? v1 : (b == 2) ? v2
                    : (b == 3) ? v3 : (b == 4) ? v4 : v5;
    int tdx = threadIdx.x;
    float s = 0.f;
    for (int c = 0; c < CC; ++c) s += gw[(size_t)tdx * CC + c] * av[c];
    wsd[b * 256 + tdx] = s;
}

// ---------------- per-node GAT logit halves ----------------
__global__ __launch_bounds__(256)
void hshd_k(const float* __restrict__ Xp, const float* __restrict__ Xs,
            const float* __restrict__ Xa, const float* __restrict__ wsd,
            float* __restrict__ hs, float* __restrict__ hd)
{
    int b = blockIdx.y, row = blockIdx.x, t = threadIdx.x;
    const float* X = (b == 0) ? Xp : (b == 1) ? Xs : Xa;
    float x = X[(size_t)row * CC + t];
    float p1 = x * wsd[b * 512 + t];
    float p2 = x * wsd[b * 512 + 256 + t];
    for (int off = 32; off; off >>= 1) {
        p1 += __shfl_down(p1, off, 64);
        p2 += __shfl_down(p2, off, 64);
    }
    __shared__ float s1[4], s2[4];
    if ((t & 63) == 0) { s1[t >> 6] = p1; s2[t >> 6] = p2; }
    __syncthreads();
    if (t == 0) {
        hs[b * NN + row] = s1[0] + s1[1] + s1[2] + s1[3];
        hd[b * NN + row] = s2[0] + s2[1] + s2[2] + s2[3];
    }
}

// ---------------- fused edge pass: wexp + adjacency bitmap + degree ----------------
__global__ __launch_bounds__(256)
void edge_k(const int* __restrict__ ei, const float* __restrict__ hs,
            const float* __restrict__ hd, float* __restrict__ wexp,
            unsigned* __restrict__ bits, int* __restrict__ cnt)
{
    int e = blockIdx.x * 256 + threadIdx.x;
    int s = ei[e], d = ei[EE + e];
    #pragma unroll
    for (int b = 0; b < 3; ++b) {
        float l = hs[b * NN + s] + hd[b * NN + d];
        l = (l > 0.f) ? l : 0.2f * l;
        wexp[(size_t)b * EE + e] = fexp(l);
    }
    size_t lin = (size_t)d * NN + s;
    atomicOr(&bits[lin >> 5], 1u << (lin & 31));
    atomicAdd(&cnt[d], 1);
}

__global__ void gcount_k(const int* __restrict__ tki, int* __restrict__ cnt)
{
    int p = blockIdx.x * 256 + threadIdx.x;
    atomicAdd(&cnt[tki[p]], 1);
}

__global__ __launch_bounds__(256)
void prefix_k(const int* __restrict__ cnt, int* __restrict__ off, int* __restrict__ cur)
{
    __shared__ int part[257];
    int t = threadIdx.x;
    int loc[16]; int s = 0;
    #pragma unroll
    for (int u = 0; u < 16; ++u) { loc[u] = s; s += cnt[t * 16 + u]; }
    part[t + 1] = s;
    if (t == 0) part[0] = 0;
    __syncthreads();
    if (t == 0) for (int i = 1; i <= 256; ++i) part[i] += part[i - 1];
    __syncthreads();
    int b = part[t];
    #pragma unroll
    for (int u = 0; u < 16; ++u) { off[t * 16 + u] = b + loc[u]; cur[t * 16 + u] = b + loc[u]; }
    if (t == 255) off[4096] = part[256];
}

__global__ void efill_k(const int* __restrict__ ei, int* __restrict__ cur,
                        int* __restrict__ lst)
{
    int e = blockIdx.x * 256 + threadIdx.x;
    int p = atomicAdd(&cur[ei[EE + e]], 1);
    lst[p] = e;
}

__global__ void gfill_k(const int* __restrict__ tki, int* __restrict__ cur,
                        int* __restrict__ lst)
{
    int p = blockIdx.x * 256 + threadIdx.x;
    int q = atomicAdd(&cur[tki[p]], 1);
    lst[q] = p;
}

// ---------------- per-column top-32: wave-private selection ----------------
// key = (fbits & ~0xF) | (15 - u): 28 value bits (2^-24 rel quantization —
// numerically invisible) + 4-bit per-lane item index. Keys unique per lane
// -> unique winner lane, branch-free cndmask removal, ONE ds_write for the
// index per round (R10's 16 predicated ds_writes were the 2x regression).
__global__ __launch_bounds__(256)
void topk_k(const float* __restrict__ EPT, const float* __restrict__ EST,
            const float* __restrict__ ivp, const float* __restrict__ ivs,
            const unsigned* __restrict__ adjbits,
            int* __restrict__ tki, float* __restrict__ tkv)
{
    __shared__ unsigned lv[4][KT];
    __shared__ int      li[4][KT];
    const int j = blockIdx.x, t = threadIdx.x;
    const int w = t >> 6, lane = t & 63;
    const size_t base = (size_t)j * NN;

    unsigned keys[16], kmax = 0;
    #pragma unroll
    for (int u = 0; u < 16; ++u) {
        int i = w * 1024 + u * 64 + lane;
        float v = EPT[base + i] * ivp[i] + EST[base + i] * ivs[i];
        if ((adjbits[(base + i) >> 5] >> (i & 31)) & 1u) v = 0.f;
        union { float f; unsigned u32; } cv; cv.f = v;
        keys[u] = (cv.u32 & 0xFFFFFFF0u) | (unsigned)(15 - u);
        kmax = keys[u] > kmax ? keys[u] : kmax;
    }

    for (int r = 0; r < KT; ++r) {
        unsigned k = kmax;
        #pragma unroll
        for (int off = 1; off < 64; off <<= 1) {
            unsigned o = __shfl_xor(k, off, 64);
            k = o > k ? o : k;
        }
        if (lane == 0) lv[w][r] = k;
        if (kmax == k) {                  // unique winner lane (keys unique per lane)
            int u_win = 15 - (int)(k & 0xFu);
            li[w][r] = w * 1024 + u_win * 64 + lane;     // single ds_write
            kmax = 0;
            #pragma unroll
            for (int u = 0; u < 16; ++u) {
                if (keys[u] == k) keys[u] = 0;           // branch-free cndmask
                kmax = keys[u] > kmax ? keys[u] : kmax;
            }
        }
    }
    __syncthreads();

    // 4-way merge (thread 0); value ties broken by lower index = reference order
    if (t == 0) {
        unsigned hv[4] = {lv[0][0], lv[1][0], lv[2][0], lv[3][0]};
        int      hi_[4] = {li[0][0], li[1][0], li[2][0], li[3][0]};
        int      pp[4] = {0, 0, 0, 0};
        for (int r = 0; r < KT; ++r) {
            int best = 0;
            #pragma unroll
            for (int wsel = 1; wsel < 4; ++wsel)
                if (hv[wsel] > hv[best] || (hv[wsel] == hv[best] && hi_[wsel] < hi_[best]))
                    best = wsel;
            union { unsigned u32; float f; } cv; cv.u32 = hv[best] & 0xFFFFFFF0u;
            tkv[j * KT + r] = cv.f;
            tki[j * KT + r] = hi_[best];
            int p = ++pp[best];
            hv[best]  = (p < KT) ? lv[best][p] : 0u;
            hi_[best] = (p < KT) ? li[best][p] : 0x7FFFFFFF;
        }
    }
}

// ---------------- aw at sparse positions + column normalize ----------------
__global__ __launch_bounds__(256)
void awcol_k(const ushort_t* __restrict__ qh, const ushort_t* __restrict__ ql,
             const ushort_t* __restrict__ kh, const ushort_t* __restrict__ kl,
             const float* __restrict__ La, const int* __restrict__ tki,
             const float* __restrict__ tkv,
             const float* agp, const float* bgp, const float* cgp,
             float* __restrict__ gn)
{
    __shared__ float kj[CC];
    __shared__ float gv[KT];
    __shared__ float cs_sh;
    int j = blockIdx.x, t = threadIdx.x;
    kj[t] = bf2f(kh[(size_t)j * CC + t]) + bf2f(kl[(size_t)j * CC + t]);
    __syncthreads();
    float hg = 0.5f * (*agp) + 0.5f * (*bgp), cg = *cgp;
    int wv = t >> 6, ln = t & 63;
    for (int k = wv; k < KT; k += 4) {
        int i = tki[j * KT + k];
        float p = 0.f;
        #pragma unroll
        for (int u = 0; u < 4; ++u) {
            int c = ln + u * 64;
            float q = bf2f(qh[(size_t)i * CC + c]) + bf2f(ql[(size_t)i * CC + c]);
            p += q * kj[c];
        }
        for (int off = 32; off; off >>= 1) p += __shfl_down(p, off, 64);
        if (ln == 0) {
            float aw = fexp(p * 0.0625f) / La[i];
            gv[k] = hg * tkv[j * KT + k] + cg * aw;
        }
    }
    __syncthreads();
    if (t == 0) { float cs = 0.f; for (int k = 0; k < KT; ++k) cs += gv[k]; cs_sh = cs; }
    __syncthreads();
    if (t < KT) gn[j * KT + t] = gv[t] / cs_sh;
}

// ---------------- unrolled broadcast gather core ----------------
__device__ __forceinline__ void gather_accum(const float* __restrict__ aem, int ln, int n,
                                             float la, int s, float4& acc)
{
    int u = 0;
    for (; u + 4 <= n; u += 4) {
        float l0 = __shfl(la, u, 64),     l1 = __shfl(la, u + 1, 64);
        float l2 = __shfl(la, u + 2, 64), l3 = __shfl(la, u + 3, 64);
        int   s0 = __shfl(s, u, 64),      s1 = __shfl(s, u + 1, 64);
        int   s2 = __shfl(s, u + 2, 64),  s3 = __shfl(s, u + 3, 64);
        const float4 v0 = *(const float4*)&aem[(size_t)s0 * CC + ln * 4];
        const float4 v1 = *(const float4*)&aem[(size_t)s1 * CC + ln * 4];
        const float4 v2 = *(const float4*)&aem[(size_t)s2 * CC + ln * 4];
        const float4 v3 = *(const float4*)&aem[(size_t)s3 * CC + ln * 4];
        acc.x += l0 * v0.x + l1 * v1.x + l2 * v2.x + l3 * v3.x;
        acc.y += l0 * v0.y + l1 * v1.y + l2 * v2.y + l3 * v3.y;
        acc.z += l0 * v0.z + l1 * v1.z + l2 * v2.z + l3 * v3.z;
        acc.w += l0 * v0.w + l1 * v1.w + l2 * v2.w + l3 * v3.w;
    }
    for (; u < n; ++u) {
        float lu = __shfl(la, u, 64);
        int   su = __shfl(s, u, 64);
        const float4 v = *(const float4*)&aem[(size_t)su * CC + ln * 4];
        acc.x += lu * v.x; acc.y += lu * v.y;
        acc.z += lu * v.z; acc.w += lu * v.w;
    }
}

// ---------------- merged local+global gather -> split bf16 into K-concat OUTC ----------------
__global__ __launch_bounds__(256)
void gather_k(const int* __restrict__ ei, const int* __restrict__ eoff,
              const int* __restrict__ elst, const float* __restrict__ wexp,
              const int* __restrict__ goff, const int* __restrict__ glst,
              const float* __restrict__ gn, const float* __restrict__ aem,
              const float* alp, const float* blp, const float* clp,
              ushort_t* __restrict__ outch, ushort_t* __restrict__ outcl)
{
    int wv = threadIdx.x >> 6, ln = threadIdx.x & 63;
    float4 acc = {0.f, 0.f, 0.f, 0.f};

    if (blockIdx.x < NN / 4) {                   // ---- local branch ----
        int d = blockIdx.x * 4 + wv;
        int beg = eoff[d], end = eoff[d + 1];

        float s1 = 0.f, s2 = 0.f, s3 = 0.f;      // softmax denominators (wave reduce)
        for (int c = beg + ln; c < end; c += 64) {
            int e = elst[c];
            s1 += wexp[e];
            s2 += wexp[EE + e];
            s3 += wexp[2 * (size_t)EE + e];
        }
        #pragma unroll
        for (int off = 1; off < 64; off <<= 1) {
            s1 += __shfl_xor(s1, off, 64);
            s2 += __shfl_xor(s2, off, 64);
            s3 += __shfl_xor(s3, off, 64);
        }
        float i0 = (*alp) / s1, i1 = (*blp) / s2, i2 = (*clp) / s3;

        for (int c = beg; c < end; c += 64) {
            int n = min(64, end - c);
            int s = 0; float la = 0.f;
            if (ln < n) {
                int e = elst[c + ln];
                s = ei[e];
                la = i0 * wexp[e] + i1 * wexp[EE + e] + i2 * wexp[2 * (size_t)EE + e];
            }
            gather_accum(aem, ln, n, la, s, acc);
        }
        float inv = 1.f / fmaxf((float)(end - beg), 1.f);
        acc.x *= inv; acc.y *= inv; acc.z *= inv; acc.w *= inv;

        ushort_t h0 = f2bf(acc.x), h1 = f2bf(acc.y), h2 = f2bf(acc.z), h3 = f2bf(acc.w);
        uint2 hw, lw;
        hw.x = (unsigned)h0 | ((unsigned)h1 << 16); hw.y = (unsigned)h2 | ((unsigned)h3 << 16);
        lw.x = (unsigned)f2bf(acc.x - bf2f(h0)) | ((unsigned)f2bf(acc.y - bf2f(h1)) << 16);
        lw.y = (unsigned)f2bf(acc.z - bf2f(h2)) | ((unsigned)f2bf(acc.w - bf2f(h3)) << 16);
        *(uint2*)&outch[(size_t)d * 512 + ln * 4] = hw;
        *(uint2*)&outcl[(size_t)d * 512 + ln * 4] = lw;
    } else {                                     // ---- global branch ----
        int i = (blockIdx.x - NN / 4) * 4 + wv;
        int beg = goff[i], end = goff[i + 1];
        for (int c = beg; c < end; c += 64) {
            int n = min(64, end - c);
            int jcol = 0; float g = 0.f;
            if (ln < n) {
                int p = glst[c + ln];
                jcol = p >> 5;
                g = gn[p];
            }
            gather_accum(aem, ln, n, g, jcol, acc);
        }
        ushort_t h0 = f2bf(acc.x), h1 = f2bf(acc.y), h2 = f2bf(acc.z), h3 = f2bf(acc.w);
        uint2 hw, lw;
        hw.x = (unsigned)h0 | ((unsigned)h1 << 16); hw.y = (unsigned)h2 | ((unsigned)h3 << 16);
        lw.x = (unsigned)f2bf(acc.x - bf2f(h0)) | ((unsigned)f2bf(acc.y - bf2f(h1)) << 16);
        lw.y = (unsigned)f2bf(acc.z - bf2f(h2)) | ((unsigned)f2bf(acc.w - bf2f(h3)) << 16);
        *(uint2*)&outch[(size_t)i * 512 + 256 + ln * 4] = hw;
        *(uint2*)&outcl[(size_t)i * 512 + 256 + ln * 4] = lw;
    }
}

__global__ void diag_k(float* out, float v) { out[0] = v; }

// ---------------- host ----------------
extern "C" void kernel_launch(void* const* d_in, const int* in_sizes, int n_in,
                              void* d_out, int out_size, void* d_ws, size_t ws_size,
                              hipStream_t stream)
{
    (void)in_sizes; (void)n_in; (void)out_size;

    if (ws_size < WS_FLOATS * sizeof(float)) {
        diag_k<<<1, 1, 0, stream>>>((float*)d_out, (float)(ws_size >> 20));
        return;
    }

    float* W = (float*)d_ws;
    float* EPT = W + OFF_EPT;  float* EST = W + OFF_EST;
    float* LP = W + OFF_LP;    float* LS = W + OFF_LS;   float* LA = W + OFF_LA;
    int* ECNT = (int*)(W + OFF_ECNT);
    int* GCNT = (int*)(W + OFF_GCNT);
    unsigned* ADJ = (unsigned*)(W + OFF_ADJ);
    float* XM = W + OFF_XM;
    ushort_t* QKS = (ushort_t*)(W + OFF_QK);
    float* WEXP = W + OFF_WEXP;
    float* HS = W + OFF_HS;    float* HD = W + OFF_HD;   float* WSD = W + OFF_WSD;
    int*   TKI = (int*)(W + OFF_TKI);
    float* TKV = W + OFF_TKV;  float* GN = W + OFF_GN;
    int* EOFF = (int*)(W + OFF_EOFF); int* ECUR = (int*)(W + OFF_ECUR);
    int* ELST = (int*)(W + OFF_ELST);
    int* GOFF = (int*)(W + OFF_GOFF); int* GCUR = (int*)(W + OFF_GCUR);
    int* GLST = (int*)(W + OFF_GLST);

    ushort_t* PRO = (ushort_t*)EPT;            // prologue scratch (dead until qk writes EPT)
    ushort_t* EPI = (ushort_t*)EST;            // epilogue scratch (dead after topk)
    ushort_t* WLT = (ushort_t*)(W + OFF_WLT);  // combined final weight (survives qk)

    ushort_t* XINH = PRO + SH_XINH; ushort_t* XINL = PRO + SH_XINL;
    ushort_t* HIDH = PRO + SH_HIDH; ushort_t* HIDL = PRO + SH_HIDL;
    ushort_t* XMH  = PRO + SH_XMH;  ushort_t* XML  = PRO + SH_XML;

    auto W1T = [&](int b, int hl) { return PRO + SH_WT + (size_t)b * WT_BR + hl * 131072; };
    auto W2T = [&](int b, int hl) { return PRO + SH_WT + (size_t)b * WT_BR + 262144 + hl * 131072; };
    auto WQT = [&](int b, int hl) { return PRO + SH_WT + (size_t)b * WT_BR + 524288 + hl * 65536; };
    auto WKT = [&](int b, int hl) { return PRO + SH_WT + (size_t)b * WT_BR + 655360 + hl * 65536; };
    ushort_t* WCT_H = WLT;            // combined [wloc;wglb]^T hi: [256 n][512 k]
    ushort_t* WCT_L = WLT + 131072;
    ushort_t* OUTCH = EPI;            // [4096][512] hi
    ushort_t* OUTCL = EPI + 2097152;  // [4096][512] lo

    auto QHp = [&](int b) { return QKS + (size_t)(b * 4 + 0) * 1048576; };
    auto QLp = [&](int b) { return QKS + (size_t)(b * 4 + 1) * 1048576; };
    auto KHp = [&](int b) { return QKS + (size_t)(b * 4 + 2) * 1048576; };
    auto KLp = [&](int b) { return QKS + (size_t)(b * 4 + 3) * 1048576; };

    // branch order [pe, se, ae] to match (a_*, b_*, c_*) coefficient order
    const float* Xin[3] = {(const float*)d_in[1], (const float*)d_in[2], (const float*)d_in[0]};
    const int base_idx[3] = {14, 25, 3};
    const float *w1[3], *b1[3], *w2[3], *b2[3], *gw[3], *asv[3], *adv[3], *wq[3], *bq[3], *wk[3], *bk[3];
    for (int b = 0; b < 3; ++b) {
        int o = base_idx[b];
        w1[b] = (const float*)d_in[o + 0]; b1[b] = (const float*)d_in[o + 1];
        w2[b] = (const float*)d_in[o + 2]; b2[b] = (const float*)d_in[o + 3];
        gw[b] = (const float*)d_in[o + 4]; asv[b] = (const float*)d_in[o + 5];
        adv[b] = (const float*)d_in[o + 6];
        wq[b] = (const float*)d_in[o + 7]; bq[b] = (const float*)d_in[o + 8];
        wk[b] = (const float*)d_in[o + 9]; bk[b] = (const float*)d_in[o + 10];
    }
    const float* al = (const float*)d_in[36]; const float* bl = (const float*)d_in[37];
    const float* cl = (const float*)d_in[38];
    const float* ag = (const float*)d_in[39]; const float* bg = (const float*)d_in[40];
    const float* cg = (const float*)d_in[41];
    const float* wloc = (const float*)d_in[42];
    const float* wglb = (const float*)d_in[43];
    const int* ei = (const int*)d_in[44];

    dim3 blk(256);

    // 0. zero accumulators
    hipMemsetAsync(LP, 0, (ZERO_END - OFF_LP) * sizeof(float), stream);

    // 0b. all weight transposes+splits in one batched launch (z = 14)
    {
        TArgs a{};
        for (int b = 0; b < 3; ++b) {
            a.s[b] = w1[b]; a.h[b] = W1T(b, 0); a.l[b] = W1T(b, 1);
            a.nshift[b] = 9; a.total[b] = 131072; a.kstride[b] = 256; a.koff[b] = 0;
            a.s[3 + b] = w2[b]; a.h[3 + b] = W2T(b, 0); a.l[3 + b] = W2T(b, 1);
            a.nshift[3 + b] = 8; a.total[3 + b] = 131072; a.kstride[3 + b] = 512; a.koff[3 + b] = 0;
            a.s[6 + b] = wq[b]; a.h[6 + b] = WQT(b, 0); a.l[6 + b] = WQT(b, 1);
            a.nshift[6 + b] = 8; a.total[6 + b] = 65536; a.kstride[6 + b] = 256; a.koff[6 + b] = 0;
            a.s[9 + b] = wk[b]; a.h[9 + b] = WKT(b, 0); a.l[9 + b] = WKT(b, 1);
            a.nshift[9 + b] = 8; a.total[9 + b] = 65536; a.kstride[9 + b] = 256; a.koff[9 + b] = 0;
        }
        a.s[12] = wloc; a.h[12] = WCT_H; a.l[12] = WCT_L;
        a.nshift[12] = 8; a.total[12] = 65536; a.kstride[12] = 512; a.koff[12] = 0;
        a.s[13] = wglb; a.h[13] = WCT_H; a.l[13] = WCT_L;
        a.nshift[13] = 8; a.total[13] = 65536; a.kstride[13] = 512; a.koff[13] = 256;
        wtrans_k<<<dim3(512, 1, 14), blk, 0, stream>>>(a);
    }

    // 0c. split inputs pe/se/ae -> hi/lo bf16
    split3_k<<<dim3(1024, 1, 3), blk, 0, stream>>>(Xin[0], Xin[1], Xin[2], XINH, XINL, 1048576);

    // 1. MLP1 batched (z=3): HID[b] = relu(X@w1+b1) -> split
    {
        MArgs a{};
        for (int b = 0; b < 3; ++b) {
            a.Ah[b] = XINH + (size_t)b * 1048576; a.Al[b] = XINL + (size_t)b * 1048576;
            a.Bh[b] = W1T(b, 0); a.Bl[b] = W1T(b, 1); a.bias[b] = b1[b];
            a.Cf[b] = nullptr;
            a.Ch[b] = HIDH + (size_t)b * 2097152; a.Cl[b] = HIDL + (size_t)b * 2097152;
        }
        mgemm_k<1><<<dim3(32, 8, 3), blk, 0, stream>>>(a, 512, 256);
    }
    // 1b. MLP2 batched (z=3): XM[b] = HID@w2+b2 -> fp32 + split
    {
        MArgs a{};
        for (int b = 0; b < 3; ++b) {
            a.Ah[b] = HIDH + (size_t)b * 2097152; a.Al[b] = HIDL + (size_t)b * 2097152;
            a.Bh[b] = W2T(b, 0); a.Bl[b] = W2T(b, 1); a.bias[b] = b2[b];
            a.Cf[b] = XM + (size_t)b * 1048576;
            a.Ch[b] = XMH + (size_t)b * 1048576; a.Cl[b] = XML + (size_t)b * 1048576;
        }
        mgemm_k<0><<<dim3(32, 4, 3), blk, 0, stream>>>(a, 256, 512);
    }

    // 2. GAT vecs + per-node halves + fused edge pass (wexp/adj/degree)
    gatvec_k<<<6, blk, 0, stream>>>(gw[0], gw[1], gw[2],
                                    asv[0], adv[0], asv[1], adv[1], asv[2], adv[2], WSD);
    hshd_k<<<dim3(NN, 3), blk, 0, stream>>>(XM, XM + 1048576, XM + 2 * 1048576, WSD, HS, HD);
    edge_k<<<EE / 256, blk, 0, stream>>>(ei, HS, HD, WEXP, ADJ, ECNT);

    // 2b. edge CSR by dst
    prefix_k<<<1, blk, 0, stream>>>(ECNT, EOFF, ECUR);
    efill_k<<<EE / 256, blk, 0, stream>>>(ei, ECUR, ELST);

    // 3. q/k projections batched (z=6) -> hi/lo bf16
    {
        MArgs a{};
        for (int b = 0; b < 3; ++b) {
            a.Ah[b] = XMH + (size_t)b * 1048576; a.Al[b] = XML + (size_t)b * 1048576;
            a.Bh[b] = WQT(b, 0); a.Bl[b] = WQT(b, 1); a.bias[b] = bq[b];
            a.Cf[b] = nullptr; a.Ch[b] = QHp(b); a.Cl[b] = QLp(b);
            a.Ah[3 + b] = a.Ah[b]; a.Al[3 + b] = a.Al[b];
            a.Bh[3 + b] = WKT(b, 0); a.Bl[3 + b] = WKT(b, 1); a.bias[3 + b] = bk[b];
            a.Cf[3 + b] = nullptr; a.Ch[3 + b] = KHp(b); a.Cl[3 + b] = KLp(b);
        }
        mgemm_k<0><<<dim3(32, 4, 6), blk, 0, stream>>>(a, 256, 256);
    }

    // 4. QK^T batched (z=3); ae branch rowsum-only
    {
        QArgs a{};
        for (int b = 0; b < 3; ++b) {
            a.qh[b] = QHp(b); a.ql[b] = QLp(b); a.kh[b] = KHp(b); a.kl[b] = KLp(b);
        }
        a.ept[0] = EPT; a.rs[0] = LP;
        a.ept[1] = EST; a.rs[1] = LS;
        a.ept[2] = nullptr; a.rs[2] = LA;
        qk_mfma_k<<<dim3(32, 32, 3), blk, 0, stream>>>(a, 0.0625f);
    }

    // 4b. Lp <- ag/Lp, Ls <- bg/Ls
    invrows_k<<<16, blk, 0, stream>>>(LP, LS, ag, bg);

    // 5. per-column top-32 of adj-masked sample_attn
    topk_k<<<NN, blk, 0, stream>>>(EPT, EST, LP, LS, ADJ, TKI, TKV);

    // 5b. global CSR by destination row i
    gcount_k<<<(NN * KT) / 256, blk, 0, stream>>>(TKI, GCNT);
    prefix_k<<<1, blk, 0, stream>>>(GCNT, GOFF, GCUR);
    gfill_k<<<(NN * KT) / 256, blk, 0, stream>>>(TKI, GCUR, GLST);

    // 6. sparse aw + column-normalized g values
    awcol_k<<<NN, blk, 0, stream>>>(QHp(2), QLp(2), KHp(2), KLp(2), LA,
                                    TKI, TKV, ag, bg, cg, GN);

    // 7/8. merged gathers write split bf16 directly into K-concat [OUTL|OUTG]
    gather_k<<<NN / 2, blk, 0, stream>>>(ei, EOFF, ELST, WEXP, GOFF, GLST, GN,
                                         XM + 2 * 1048576, al, bl, cl, OUTCH, OUTCL);

    // 9. out = [OUTL|OUTG] @ [wloc;wglb]  (single K=512 MFMA GEMM)
    {
        MArgs a{};
        a.Ah[0] = OUTCH; a.Al[0] = OUTCL;
        a.Bh[0] = WCT_H; a.Bl[0] = WCT_L; a.bias[0] = nullptr;
        a.Cf[0] = (float*)d_out; a.Ch[0] = nullptr; a.Cl[0] = nullptr;
        mgemm_k<0><<<dim3(32, 4, 1), blk, 0, stream>>>(a, 256, 512);
    }
}

// Round 12
// 529.905 us; speedup vs baseline: 1.1628x; 1.0456x over previous
//
#include <hip/hip_runtime.h>

#define NN 4096
#define CC 256
#define EE 131072
#define KT 32

typedef unsigned short ushort_t;
typedef __attribute__((ext_vector_type(8))) short short8;   // bf16x8 (4 VGPRs)
typedef __attribute__((ext_vector_type(4))) float float4v;  // fp32x4 acc

__device__ __forceinline__ ushort_t f2bf(float x) {
    union { float f; unsigned u; } a; a.f = x;
    unsigned r = (a.u + 0x7FFF + ((a.u >> 16) & 1)) >> 16;   // RNE
    return (ushort_t)r;
}
__device__ __forceinline__ float bf2f(ushort_t b) {
    union { float f; unsigned u; } a; a.u = ((unsigned)b) << 16;
    return a.f;
}
// fast exp: v_exp_f32 is exp2 (~1 ulp); inputs bounded |x| < ~15 here
__device__ __forceinline__ float fexp(float x) {
#if __has_builtin(__builtin_amdgcn_exp2f)
    return __builtin_amdgcn_exp2f(x * 1.4426950408889634f);
#else
    return exp2f(x * 1.4426950408889634f);
#endif
}

// ---------------- workspace layout (float slots) ----------------
constexpr size_t OFF_EPT  = 0;                         // exp(pe logits)^T [j][i] 4096x4096
constexpr size_t OFF_EST  = OFF_EPT + 16777216;        // exp(se logits)^T
// --- zero region ---
constexpr size_t OFF_LP   = OFF_EST + 16777216;        // -> ag/Lp after invrows
constexpr size_t OFF_LS   = OFF_LP + 4096;
constexpr size_t OFF_LA   = OFF_LS + 4096;
constexpr size_t OFF_ECNT = OFF_LA + 4096;             // int: in-degree per dst
constexpr size_t OFF_GCNT = OFF_ECNT + 4096;           // int: global-entry count per row i
constexpr size_t OFF_ADJ  = OFF_GCNT + 4096;           // 524288 u32 adjacency bitmap [dst][src]
constexpr size_t ZERO_END = OFF_ADJ + 524288;
// --- non-zeroed ---
constexpr size_t OFF_XM   = ZERO_END;                  // pe_m, se_m, ae_m fp32 (3 x 4096x256)
constexpr size_t OFF_QK   = OFF_XM + 3*1048576;        // 12 bf16 arrays: (qh,ql,kh,kl) x 3 branch
constexpr size_t OFF_WEXP = OFF_QK + 6*1048576;        // 3*E exp(edge logits)
constexpr size_t OFF_HS   = OFF_WEXP + 3*131072;       // 3*4096
constexpr size_t OFF_HD   = OFF_HS + 12288;
constexpr size_t OFF_WSD  = OFF_HD + 12288;            // 6*256 fused gat vecs
constexpr size_t OFF_TKI  = OFF_WSD + 1536;            // topk indices (int) 4096*32
constexpr size_t OFF_TKV  = OFF_TKI + 131072;          // topk sample values
constexpr size_t OFF_GN   = OFF_TKV + 131072;          // normalized g values
constexpr size_t OFF_EOFF = OFF_GN + 131072;           // int 4097 csr offsets (edges by dst)
constexpr size_t OFF_ECUR = OFF_EOFF + 4097;           // int 4096 fill cursors
constexpr size_t OFF_ELST = OFF_ECUR + 4096;           // int E edge ids
constexpr size_t OFF_GOFF = OFF_ELST + 131072;         // int 4097
constexpr size_t OFF_GCUR = OFF_GOFF + 4097;           // int 4096
constexpr size_t OFF_GLST = OFF_GCUR + 4096;           // int N*K entry ids
constexpr size_t OFF_WLT  = OFF_GLST + 131072;         // combined [wloc;wglb]^T hi+lo (262144 shorts)
constexpr size_t WS_FLOATS = OFF_WLT + 131072;         // ~189 MiB

// -- transient bf16 sub-layouts (short offsets) --
constexpr size_t SH_XINH = 0;                          // 3 x 1M
constexpr size_t SH_XINL = 3145728;
constexpr size_t SH_HIDH = 6291456;                    // 3 x 2M
constexpr size_t SH_HIDL = 12582912;
constexpr size_t SH_XMH  = 18874368;                   // 3 x 1M
constexpr size_t SH_XML  = 22020096;
constexpr size_t SH_WT   = 25165824;                   // per-branch transposed weights
constexpr size_t WT_BR   = 786432;                     // shorts per branch

// ---------------- batched weight transpose + split ----------------
struct TArgs {
    const float* s[14]; ushort_t* h[14]; ushort_t* l[14];
    int nshift[14]; int total[14]; int kstride[14]; int koff[14];
};

__global__ __launch_bounds__(256)
void wtrans_k(TArgs a)
{
    int z = blockIdx.z;
    int idx = blockIdx.x * 256 + threadIdx.x;
    if (idx >= a.total[z]) return;
    int n = idx & ((1 << a.nshift[z]) - 1);
    int k = idx >> a.nshift[z];
    float v = a.s[z][idx];
    ushort_t hh = f2bf(v);
    size_t o = (size_t)n * a.kstride[z] + a.koff[z] + k;
    a.h[z][o] = hh;
    a.l[z][o] = f2bf(v - bf2f(hh));
}

// ---------------- activation split: h/l bf16 copies ----------------
__global__ __launch_bounds__(256)
void split3_k(const float* s0, const float* s1, const float* s2,
              ushort_t* hb, ushort_t* lb, size_t nper)
{
    int z = blockIdx.z;
    const float* s = (z == 0) ? s0 : (z == 1) ? s1 : s2;
    ushort_t* h = hb + (size_t)z * nper;
    ushort_t* l = lb + (size_t)z * nper;
    size_t i = (size_t)(blockIdx.x * 256 + threadIdx.x) * 4;
    float4 v = *(const float4*)(s + i);
    ushort_t h0 = f2bf(v.x), h1 = f2bf(v.y), h2 = f2bf(v.z), h3 = f2bf(v.w);
    ushort_t l0 = f2bf(v.x - bf2f(h0)), l1 = f2bf(v.y - bf2f(h1));
    ushort_t l2 = f2bf(v.z - bf2f(h2)), l3 = f2bf(v.w - bf2f(h3));
    uint2 hw, lw;
    hw.x = (unsigned)h0 | ((unsigned)h1 << 16); hw.y = (unsigned)h2 | ((unsigned)h3 << 16);
    lw.x = (unsigned)l0 | ((unsigned)l1 << 16); lw.y = (unsigned)l2 | ((unsigned)l3 << 16);
    *(uint2*)(h + i) = hw;
    *(uint2*)(l + i) = lw;
}

// ---------------- batched bf16x3 MFMA GEMM: C[z] = A[z] @ B[z]^T ----------------
struct MArgs {
    const ushort_t* Ah[6]; const ushort_t* Al[6];
    const ushort_t* Bh[6]; const ushort_t* Bl[6];
    const float* bias[6];
    float* Cf[6]; ushort_t* Ch[6]; ushort_t* Cl[6];
};

template<int RELU>
__global__ __launch_bounds__(256)
void mgemm_k(MArgs a, int N, int K)
{
    __shared__ ushort_t SA[2][128 * 32];
    __shared__ ushort_t SB[2][64 * 32];

    const int z = blockIdx.z;
    const int t = threadIdx.x, wave = t >> 6, lane = t & 63;
    const int lrow = lane & 15, lquad = lane >> 4;

    const ushort_t* src = (wave == 0) ? a.Ah[z] : (wave == 1) ? a.Al[z]
                        : (wave == 2) ? a.Bh[z] : a.Bl[z];
    ushort_t* dst = (wave == 0) ? &SA[0][0] : (wave == 1) ? &SA[1][0]
                  : (wave == 2) ? &SB[0][0] : &SB[1][0];
    const int rbase = (wave < 2) ? blockIdx.x * 128 : blockIdx.y * 64;
    const int sr = lane >> 2, sq = lane & 3;
    const int gsq = sq ^ ((sr >> 1) & 3);          // staging-side swizzle

    float4v acc[2][4] = {};

    for (int k0 = 0; k0 < K; k0 += 32) {
        if (wave < 2) {
            #pragma unroll
            for (int it = 0; it < 8; ++it) {
                const ushort_t* g = src + (size_t)(rbase + it * 16 + sr) * K + k0 + gsq * 8;
                __builtin_amdgcn_global_load_lds(
                    (const __attribute__((address_space(1))) void*)g,
                    (__attribute__((address_space(3))) void*)(dst + it * 512),
                    16, 0, 0);
            }
        } else {
            #pragma unroll
            for (int it = 0; it < 4; ++it) {
                const ushort_t* g = src + (size_t)(rbase + it * 16 + sr) * K + k0 + gsq * 8;
                __builtin_amdgcn_global_load_lds(
                    (const __attribute__((address_space(1))) void*)g,
                    (__attribute__((address_space(3))) void*)(dst + it * 512),
                    16, 0, 0);
            }
        }
        __syncthreads();

        short8 fAh[2], fAl[2], fBh[4], fBl[4];
        #pragma unroll
        for (int mt = 0; mt < 2; ++mt) {
            int ra = wave * 32 + mt * 16 + lrow;
            int ca = (lquad ^ ((ra >> 1) & 3)) * 8;
            fAh[mt] = *(const short8*)&SA[0][ra * 32 + ca];
            fAl[mt] = *(const short8*)&SA[1][ra * 32 + ca];
        }
        #pragma unroll
        for (int nt = 0; nt < 4; ++nt) {
            int rb = nt * 16 + lrow;
            int cb = (lquad ^ ((rb >> 1) & 3)) * 8;
            fBh[nt] = *(const short8*)&SB[0][rb * 32 + cb];
            fBl[nt] = *(const short8*)&SB[1][rb * 32 + cb];
        }
        #pragma unroll
        for (int mt = 0; mt < 2; ++mt)
            #pragma unroll
            for (int nt = 0; nt < 4; ++nt) {
                acc[mt][nt] = __builtin_amdgcn_mfma_f32_16x16x32_bf16(fAh[mt], fBh[nt], acc[mt][nt], 0, 0, 0);
                acc[mt][nt] = __builtin_amdgcn_mfma_f32_16x16x32_bf16(fAh[mt], fBl[nt], acc[mt][nt], 0, 0, 0);
                acc[mt][nt] = __builtin_amdgcn_mfma_f32_16x16x32_bf16(fAl[mt], fBh[nt], acc[mt][nt], 0, 0, 0);
            }
        __syncthreads();
    }

    const float* bias = a.bias[z];
    float* Cf = a.Cf[z];
    ushort_t* Ch = a.Ch[z]; ushort_t* Cl = a.Cl[z];
    const int i0w = blockIdx.x * 128 + wave * 32, j0w = blockIdx.y * 64;
    #pragma unroll
    for (int mt = 0; mt < 2; ++mt) {
        const int ib = i0w + mt * 16 + lquad * 4;
        #pragma unroll
        for (int nt = 0; nt < 4; ++nt) {
            const int j = j0w + nt * 16 + lrow;
            float bj = bias ? bias[j] : 0.f;
            #pragma unroll
            for (int r = 0; r < 4; ++r) {
                float v = acc[mt][nt][r] + bj;
                if (RELU) v = fmaxf(v, 0.f);
                if (Cf) Cf[(size_t)(ib + r) * N + j] = v;
                if (Ch) {
                    ushort_t h = f2bf(v);
                    Ch[(size_t)(ib + r) * N + j] = h;
                    Cl[(size_t)(ib + r) * N + j] = f2bf(v - bf2f(h));
                }
            }
        }
    }
}

// ---------------- batched bf16x3 MFMA QK^T (swizzled, fast exp) ----------------
struct QArgs {
    const ushort_t* qh[3]; const ushort_t* ql[3];
    const ushort_t* kh[3]; const ushort_t* kl[3];
    float* ept[3]; float* rs[3];
};

__global__ __launch_bounds__(256)
void qk_mfma_k(QArgs a, float scale)
{
    __shared__ ushort_t SA[2][128 * 32];
    __shared__ ushort_t SB[2][128 * 32];

    const int z = blockIdx.z;
    const int t = threadIdx.x;
    const int wave = t >> 6, lane = t & 63;
    const int wi = wave & 1, wj = wave >> 1;
    const int i0w = blockIdx.x * 128 + wi * 64;
    const int j0w = blockIdx.y * 128 + wj * 64;
    const int lrow = lane & 15, lquad = lane >> 4;

    const ushort_t* src = (wave == 0) ? a.qh[z] : (wave == 1) ? a.ql[z]
                        : (wave == 2) ? a.kh[z] : a.kl[z];
    ushort_t* dst = (wave == 0) ? &SA[0][0] : (wave == 1) ? &SA[1][0]
                  : (wave == 2) ? &SB[0][0] : &SB[1][0];
    const int rbase = (wave < 2) ? blockIdx.x * 128 : blockIdx.y * 128;
    const int sr = lane >> 2, sq = lane & 3;
    const int gsq = sq ^ ((sr >> 1) & 3);

    float4v acc[4][4] = {};

    for (int k0 = 0; k0 < CC; k0 += 32) {
        #pragma unroll
        for (int it = 0; it < 8; ++it) {
            const ushort_t* g = src + (size_t)(rbase + it * 16 + sr) * CC + k0 + gsq * 8;
            __builtin_amdgcn_global_load_lds(
                (const __attribute__((address_space(1))) void*)g,
                (__attribute__((address_space(3))) void*)(dst + it * 512),
                16, 0, 0);
        }
        __syncthreads();

        short8 Ah[4], Al[4], Bh[4], Bl[4];
        #pragma unroll
        for (int mt = 0; mt < 4; ++mt) {
            int ra = wi * 64 + mt * 16 + lrow;
            int ca = (lquad ^ ((ra >> 1) & 3)) * 8;
            Ah[mt] = *(const short8*)&SA[0][ra * 32 + ca];
            Al[mt] = *(const short8*)&SA[1][ra * 32 + ca];
        }
        #pragma unroll
        for (int nt = 0; nt < 4; ++nt) {
            int rb = wj * 64 + nt * 16 + lrow;
            int cb = (lquad ^ ((rb >> 1) & 3)) * 8;
            Bh[nt] = *(const short8*)&SB[0][rb * 32 + cb];
            Bl[nt] = *(const short8*)&SB[1][rb * 32 + cb];
        }
        #pragma unroll
        for (int mt = 0; mt < 4; ++mt)
            #pragma unroll
            for (int nt = 0; nt < 4; ++nt) {
                acc[mt][nt] = __builtin_amdgcn_mfma_f32_16x16x32_bf16(Ah[mt], Bh[nt], acc[mt][nt], 0, 0, 0);
                acc[mt][nt] = __builtin_amdgcn_mfma_f32_16x16x32_bf16(Ah[mt], Bl[nt], acc[mt][nt], 0, 0, 0);
                acc[mt][nt] = __builtin_amdgcn_mfma_f32_16x16x32_bf16(Al[mt], Bh[nt], acc[mt][nt], 0, 0, 0);
            }
        __syncthreads();
    }

    float* ept = a.ept[z];
    float* rowsum = a.rs[z];
    #pragma unroll
    for (int mt = 0; mt < 4; ++mt) {
        const int ib = i0w + mt * 16 + lquad * 4;
        float part[4] = {0.f, 0.f, 0.f, 0.f};
        #pragma unroll
        for (int nt = 0; nt < 4; ++nt) {
            const int j = j0w + nt * 16 + lrow;
            float e0 = fexp(acc[mt][nt][0] * scale);
            float e1 = fexp(acc[mt][nt][1] * scale);
            float e2 = fexp(acc[mt][nt][2] * scale);
            float e3 = fexp(acc[mt][nt][3] * scale);
            part[0] += e0; part[1] += e1; part[2] += e2; part[3] += e3;
            if (ept)
                *(float4*)&ept[(size_t)j * NN + ib] = make_float4(e0, e1, e2, e3);
        }
        #pragma unroll
        for (int r = 0; r < 4; ++r) {
            float p = part[r];
            p += __shfl_xor(p, 1, 64);
            p += __shfl_xor(p, 2, 64);
            p += __shfl_xor(p, 4, 64);
            p += __shfl_xor(p, 8, 64);
            if (lrow == 0) atomicAdd(&rowsum[ib + r], p);
        }
    }
}

// ---------------- in-place row-sum reciprocal scaling ----------------
__global__ void invrows_k(float* __restrict__ lp, float* __restrict__ ls,
                          const float* agp, const float* bgp)
{
    int i = blockIdx.x * 256 + threadIdx.x;
    lp[i] = (*agp) / lp[i];
    ls[i] = (*bgp) / ls[i];
}

// ---------------- fused GAT vectors: w = gw @ a  (6 of them) ----------------
__global__ __launch_bounds__(256)
void gatvec_k(const float* g0, const float* g1, const float* g2,
              const float* v0, const float* v1, const float* v2,
              const float* v3, const float* v4, const float* v5,
              float* __restrict__ wsd)
{
    int b = blockIdx.x;
    const float* gw = (b < 2) ? g0 : (b < 4) ? g1 : g2;
    const float* av = (b == 0) ? v0 : (b == 1) ? v1 : (b == 2) ? v2
                    : (b == 3) ? v3 : (b == 4) ? v4 : v5;
    int tdx = threadIdx.x;
    float s = 0.f;
    for (int c = 0; c < CC; ++c) s += gw[(size_t)tdx * CC + c] * av[c];
    wsd[b * 256 + tdx] = s;
}

// ---------------- per-node GAT logit halves ----------------
__global__ __launch_bounds__(256)
void hshd_k(const float* __restrict__ Xp, const float* __restrict__ Xs,
            const float* __restrict__ Xa, const float* __restrict__ wsd,
            float* __restrict__ hs, float* __restrict__ hd)
{
    int b = blockIdx.y, row = blockIdx.x, t = threadIdx.x;
    const float* X = (b == 0) ? Xp : (b == 1) ? Xs : Xa;
    float x = X[(size_t)row * CC + t];
    float p1 = x * wsd[b * 512 + t];
    float p2 = x * wsd[b * 512 + 256 + t];
    for (int off = 32; off; off >>= 1) {
        p1 += __shfl_down(p1, off, 64);
        p2 += __shfl_down(p2, off, 64);
    }
    __shared__ float s1[4], s2[4];
    if ((t & 63) == 0) { s1[t >> 6] = p1; s2[t >> 6] = p2; }
    __syncthreads();
    if (t == 0) {
        hs[b * NN + row] = s1[0] + s1[1] + s1[2] + s1[3];
        hd[b * NN + row] = s2[0] + s2[1] + s2[2] + s2[3];
    }
}

// ---------------- fused edge pass: wexp + adjacency bitmap + degree ----------------
__global__ __launch_bounds__(256)
void edge_k(const int* __restrict__ ei, const float* __restrict__ hs,
            const float* __restrict__ hd, float* __restrict__ wexp,
            unsigned* __restrict__ bits, int* __restrict__ cnt)
{
    int e = blockIdx.x * 256 + threadIdx.x;
    int s = ei[e], d = ei[EE + e];
    #pragma unroll
    for (int b = 0; b < 3; ++b) {
        float l = hs[b * NN + s] + hd[b * NN + d];
        l = (l > 0.f) ? l : 0.2f * l;
        wexp[(size_t)b * EE + e] = fexp(l);
    }
    size_t lin = (size_t)d * NN + s;
    atomicOr(&bits[lin >> 5], 1u << (lin & 31));
    atomicAdd(&cnt[d], 1);
}

// ---------------- parallel exclusive prefix over 4096 counters ----------------
__global__ __launch_bounds__(256)
void prefix_k(const int* __restrict__ cnt, int* __restrict__ off, int* __restrict__ cur)
{
    __shared__ int wsum[4];
    int t = threadIdx.x, lane = t & 63, w = t >> 6;
    int loc[16]; int s = 0;
    #pragma unroll
    for (int u = 0; u < 16; ++u) { loc[u] = s; s += cnt[t * 16 + u]; }
    int v = s;
    #pragma unroll
    for (int d = 1; d < 64; d <<= 1) {
        int o = __shfl_up(v, d, 64);
        if (lane >= d) v += o;
    }
    if (lane == 63) wsum[w] = v;
    __syncthreads();
    int base = 0;
    #pragma unroll
    for (int x = 0; x < 3; ++x) base += (x < w) ? wsum[x] : 0;
    int excl = base + v - s;
    #pragma unroll
    for (int u = 0; u < 16; ++u) {
        off[t * 16 + u] = excl + loc[u];
        cur[t * 16 + u] = excl + loc[u];
    }
    if (t == 255) off[4096] = base + v;
}

__global__ void efill_k(const int* __restrict__ ei, int* __restrict__ cur,
                        int* __restrict__ lst)
{
    int e = blockIdx.x * 256 + threadIdx.x;
    int p = atomicAdd(&cur[ei[EE + e]], 1);
    lst[p] = e;
}

// ---------------- per-column top-32: wave-private selection, top-4 queue ----------------
// key = (fbits & ~0xF) | (15 - u): 28 value bits + 4-bit per-lane item index.
// Per-lane sorted top-4 queue (m0..m3): winner shifts the queue (~10 ops)
// instead of a 48-op rescan; exact refill from keys[]+consumed mask triggers
// only on a lane's 5th win (rare). Fused gcount (lanes<32 atomics at end).
__global__ __launch_bounds__(256)
void topk_k(const float* __restrict__ EPT, const float* __restrict__ EST,
            const float* __restrict__ ivp, const float* __restrict__ ivs,
            const unsigned* __restrict__ adjbits,
            int* __restrict__ tki, float* __restrict__ tkv,
            int* __restrict__ gcnt)
{
    __shared__ unsigned lv[4][KT];
    __shared__ int      li[4][KT];
    const int j = blockIdx.x, t = threadIdx.x;
    const int w = t >> 6, lane = t & 63;
    const size_t base = (size_t)j * NN;

    unsigned keys[16];
    unsigned m0 = 0, m1 = 0, m2 = 0, m3 = 0;
    #pragma unroll
    for (int u = 0; u < 16; ++u) {
        int i = w * 1024 + u * 64 + lane;
        float v = EPT[base + i] * ivp[i] + EST[base + i] * ivs[i];
        if ((adjbits[(base + i) >> 5] >> (i & 31)) & 1u) v = 0.f;
        union { float f; unsigned u32; } cv; cv.f = v;
        unsigned k = (cv.u32 & 0xFFFFFFF0u) | (unsigned)(15 - u);
        keys[u] = k;
        bool g0 = k > m0, g1 = k > m1, g2 = k > m2, g3 = k > m3;
        m3 = g3 ? (g2 ? m2 : k) : m3;
        m2 = g2 ? (g1 ? m1 : k) : m2;
        m1 = g1 ? (g0 ? m0 : k) : m1;
        m0 = g0 ? k : m0;
    }

    unsigned consumed = 0;
    for (int r = 0; r < KT; ++r) {
        unsigned k = m0;
        #pragma unroll
        for (int off = 1; off < 64; off <<= 1) {
            unsigned o = __shfl_xor(k, off, 64);
            k = o > k ? o : k;
        }
        if (lane == 0) lv[w][r] = k;
        if (m0 == k) {                    // unique winner lane (keys unique per lane)
            int u_win = 15 - (int)(k & 0xFu);
            li[w][r] = w * 1024 + u_win * 64 + lane;
            consumed |= (1u << u_win);
            m0 = m1; m1 = m2; m2 = m3; m3 = 0;
            if (m0 == 0) {                // queue exhausted: exact refill (rare)
                #pragma unroll
                for (int u = 0; u < 16; ++u) {
                    unsigned kk = ((consumed >> u) & 1u) ? 0u : keys[u];
                    bool g0 = kk > m0, g1 = kk > m1, g2 = kk > m2, g3 = kk > m3;
                    m3 = g3 ? (g2 ? m2 : kk) : m3;
                    m2 = g2 ? (g1 ? m1 : kk) : m2;
                    m1 = g1 ? (g0 ? m0 : kk) : m1;
                    m0 = g0 ? kk : m0;
                }
            }
        }
    }
    __syncthreads();

    // 4-way merge (thread 0); value ties broken by lower index = reference order
    if (t == 0) {
        unsigned hv[4] = {lv[0][0], lv[1][0], lv[2][0], lv[3][0]};
        int      hi_[4] = {li[0][0], li[1][0], li[2][0], li[3][0]};
        int      pp[4] = {0, 0, 0, 0};
        for (int r = 0; r < KT; ++r) {
            int best = 0;
            #pragma unroll
            for (int wsel = 1; wsel < 4; ++wsel)
                if (hv[wsel] > hv[best] || (hv[wsel] == hv[best] && hi_[wsel] < hi_[best]))
                    best = wsel;
            union { unsigned u32; float f; } cv; cv.u32 = hv[best] & 0xFFFFFFF0u;
            tkv[j * KT + r] = cv.f;
            tki[j * KT + r] = hi_[best];
            int p = ++pp[best];
            hv[best]  = (p < KT) ? lv[best][p] : 0u;
            hi_[best] = (p < KT) ? li[best][p] : 0x7FFFFFFF;
        }
    }
    __syncthreads();

    // fused gcount: one atomic per selected entry
    if (t < KT) atomicAdd(&gcnt[tki[j * KT + t]], 1);
}

// ---------------- aw at sparse positions + column normalize + fused gfill ----------------
__global__ __launch_bounds__(256)
void awcol_k(const ushort_t* __restrict__ qh, const ushort_t* __restrict__ ql,
             const ushort_t* __restrict__ kh, const ushort_t* __restrict__ kl,
             const float* __restrict__ La, const int* __restrict__ tki,
             const float* __restrict__ tkv,
             const float* agp, const float* bgp, const float* cgp,
             float* __restrict__ gn,
             int* __restrict__ gcur, int* __restrict__ glst)
{
    __shared__ float kj[CC];
    __shared__ float gv[KT];
    __shared__ float cs_sh;
    int j = blockIdx.x, t = threadIdx.x;

    // fused gfill: CSR entry list by destination row i
    if (t < KT) {
        int p = j * KT + t;
        int q = atomicAdd(&gcur[tki[p]], 1);
        glst[q] = p;
    }

    kj[t] = bf2f(kh[(size_t)j * CC + t]) + bf2f(kl[(size_t)j * CC + t]);
    __syncthreads();
    float hg = 0.5f * (*agp) + 0.5f * (*bgp), cg = *cgp;
    int wv = t >> 6, ln = t & 63;
    for (int k = wv; k < KT; k += 4) {
        int i = tki[j * KT + k];
        float p = 0.f;
        #pragma unroll
        for (int u = 0; u < 4; ++u) {
            int c = ln + u * 64;
            float q = bf2f(qh[(size_t)i * CC + c]) + bf2f(ql[(size_t)i * CC + c]);
            p += q * kj[c];
        }
        for (int off = 32; off; off >>= 1) p += __shfl_down(p, off, 64);
        if (ln == 0) {
            float aw = fexp(p * 0.0625f) / La[i];
            gv[k] = hg * tkv[j * KT + k] + cg * aw;
        }
    }
    __syncthreads();
    if (t == 0) { float cs = 0.f; for (int k = 0; k < KT; ++k) cs += gv[k]; cs_sh = cs; }
    __syncthreads();
    if (t < KT) gn[j * KT + t] = gv[t] / cs_sh;
}

// ---------------- unrolled broadcast gather core ----------------
__device__ __forceinline__ void gather_accum(const float* __restrict__ aem, int ln, int n,
                                             float la, int s, float4& acc)
{
    int u = 0;
    for (; u + 4 <= n; u += 4) {
        float l0 = __shfl(la, u, 64),     l1 = __shfl(la, u + 1, 64);
        float l2 = __shfl(la, u + 2, 64), l3 = __shfl(la, u + 3, 64);
        int   s0 = __shfl(s, u, 64),      s1 = __shfl(s, u + 1, 64);
        int   s2 = __shfl(s, u + 2, 64),  s3 = __shfl(s, u + 3, 64);
        const float4 v0 = *(const float4*)&aem[(size_t)s0 * CC + ln * 4];
        const float4 v1 = *(const float4*)&aem[(size_t)s1 * CC + ln * 4];
        const float4 v2 = *(const float4*)&aem[(size_t)s2 * CC + ln * 4];
        const float4 v3 = *(const float4*)&aem[(size_t)s3 * CC + ln * 4];
        acc.x += l0 * v0.x + l1 * v1.x + l2 * v2.x + l3 * v3.x;
        acc.y += l0 * v0.y + l1 * v1.y + l2 * v2.y + l3 * v3.y;
        acc.z += l0 * v0.z + l1 * v1.z + l2 * v2.z + l3 * v3.z;
        acc.w += l0 * v0.w + l1 * v1.w + l2 * v2.w + l3 * v3.w;
    }
    for (; u < n; ++u) {
        float lu = __shfl(la, u, 64);
        int   su = __shfl(s, u, 64);
        const float4 v = *(const float4*)&aem[(size_t)su * CC + ln * 4];
        acc.x += lu * v.x; acc.y += lu * v.y;
        acc.z += lu * v.z; acc.w += lu * v.w;
    }
}

// ---------------- merged local+global gather -> split bf16 into K-concat OUTC ----------------
__global__ __launch_bounds__(256)
void gather_k(const int* __restrict__ ei, const int* __restrict__ eoff,
              const int* __restrict__ elst, const float* __restrict__ wexp,
              const int* __restrict__ goff, const int* __restrict__ glst,
              const float* __restrict__ gn, const float* __restrict__ aem,
              const float* alp, const float* blp, const float* clp,
              ushort_t* __restrict__ outch, ushort_t* __restrict__ outcl)
{
    int wv = threadIdx.x >> 6, ln = threadIdx.x & 63;
    float4 acc = {0.f, 0.f, 0.f, 0.f};

    if (blockIdx.x < NN / 4) {                   // ---- local branch ----
        int d = blockIdx.x * 4 + wv;
        int beg = eoff[d], end = eoff[d + 1];

        float s1 = 0.f, s2 = 0.f, s3 = 0.f;      // softmax denominators (wave reduce)
        for (int c = beg + ln; c < end; c += 64) {
            int e = elst[c];
            s1 += wexp[e];
            s2 += wexp[EE + e];
            s3 += wexp[2 * (size_t)EE + e];
        }
        #pragma unroll
        for (int off = 1; off < 64; off <<= 1) {
            s1 += __shfl_xor(s1, off, 64);
            s2 += __shfl_xor(s2, off, 64);
            s3 += __shfl_xor(s3, off, 64);
        }
        float i0 = (*alp) / s1, i1 = (*blp) / s2, i2 = (*clp) / s3;

        for (int c = beg; c < end; c += 64) {
            int n = min(64, end - c);
            int s = 0; float la = 0.f;
            if (ln < n) {
                int e = elst[c + ln];
                s = ei[e];
                la = i0 * wexp[e] + i1 * wexp[EE + e] + i2 * wexp[2 * (size_t)EE + e];
            }
            gather_accum(aem, ln, n, la, s, acc);
        }
        float inv = 1.f / fmaxf((float)(end - beg), 1.f);
        acc.x *= inv; acc.y *= inv; acc.z *= inv; acc.w *= inv;

        ushort_t h0 = f2bf(acc.x), h1 = f2bf(acc.y), h2 = f2bf(acc.z), h3 = f2bf(acc.w);
        uint2 hw, lw;
        hw.x = (unsigned)h0 | ((unsigned)h1 << 16); hw.y = (unsigned)h2 | ((unsigned)h3 << 16);
        lw.x = (unsigned)f2bf(acc.x - bf2f(h0)) | ((unsigned)f2bf(acc.y - bf2f(h1)) << 16);
        lw.y = (unsigned)f2bf(acc.z - bf2f(h2)) | ((unsigned)f2bf(acc.w - bf2f(h3)) << 16);
        *(uint2*)&outch[(size_t)d * 512 + ln * 4] = hw;
        *(uint2*)&outcl[(size_t)d * 512 + ln * 4] = lw;
    } else {                                     // ---- global branch ----
        int i = (blockIdx.x - NN / 4) * 4 + wv;
        int beg = goff[i], end = goff[i + 1];
        for (int c = beg; c < end; c += 64) {
            int n = min(64, end - c);
            int jcol = 0; float g = 0.f;
            if (ln < n) {
                int p = glst[c + ln];
                jcol = p >> 5;
                g = gn[p];
            }
            gather_accum(aem, ln, n, g, jcol, acc);
        }
        ushort_t h0 = f2bf(acc.x), h1 = f2bf(acc.y), h2 = f2bf(acc.z), h3 = f2bf(acc.w);
        uint2 hw, lw;
        hw.x = (unsigned)h0 | ((unsigned)h1 << 16); hw.y = (unsigned)h2 | ((unsigned)h3 << 16);
        lw.x = (unsigned)f2bf(acc.x - bf2f(h0)) | ((unsigned)f2bf(acc.y - bf2f(h1)) << 16);
        lw.y = (unsigned)f2bf(acc.z - bf2f(h2)) | ((unsigned)f2bf(acc.w - bf2f(h3)) << 16);
        *(uint2*)&outch[(size_t)i * 512 + 256 + ln * 4] = hw;
        *(uint2*)&outcl[(size_t)i * 512 + 256 + ln * 4] = lw;
    }
}

__global__ void diag_k(float* out, float v) { out[0] = v; }

// ---------------- host ----------------
extern "C" void kernel_launch(void* const* d_in, const int* in_sizes, int n_in,
                              void* d_out, int out_size, void* d_ws, size_t ws_size,
                              hipStream_t stream)
{
    (void)in_sizes; (void)n_in; (void)out_size;

    if (ws_size < WS_FLOATS * sizeof(float)) {
        diag_k<<<1, 1, 0, stream>>>((float*)d_out, (float)(ws_size >> 20));
        return;
    }

    float* W = (float*)d_ws;
    float* EPT = W + OFF_EPT;  float* EST = W + OFF_EST;
    float* LP = W + OFF_LP;    float* LS = W + OFF_LS;   float* LA = W + OFF_LA;
    int* ECNT = (int*)(W + OFF_ECNT);
    int* GCNT = (int*)(W + OFF_GCNT);
    unsigned* ADJ = (unsigned*)(W + OFF_ADJ);
    float* XM = W + OFF_XM;
    ushort_t* QKS = (ushort_t*)(W + OFF_QK);
    float* WEXP = W + OFF_WEXP;
    float* HS = W + OFF_HS;    float* HD = W + OFF_HD;   float* WSD = W + OFF_WSD;
    int*   TKI = (int*)(W + OFF_TKI);
    float* TKV = W + OFF_TKV;  float* GN = W + OFF_GN;
    int* EOFF = (int*)(W + OFF_EOFF); int* ECUR = (int*)(W + OFF_ECUR);
    int* ELST = (int*)(W + OFF_ELST);
    int* GOFF = (int*)(W + OFF_GOFF); int* GCUR = (int*)(W + OFF_GCUR);
    int* GLST = (int*)(W + OFF_GLST);

    ushort_t* PRO = (ushort_t*)EPT;            // prologue scratch (dead until qk writes EPT)
    ushort_t* EPI = (ushort_t*)EST;            // epilogue scratch (dead after topk)
    ushort_t* WLT = (ushort_t*)(W + OFF_WLT);  // combined final weight (survives qk)

    ushort_t* XINH = PRO + SH_XINH; ushort_t* XINL = PRO + SH_XINL;
    ushort_t* HIDH = PRO + SH_HIDH; ushort_t* HIDL = PRO + SH_HIDL;
    ushort_t* XMH  = PRO + SH_XMH;  ushort_t* XML  = PRO + SH_XML;

    auto W1T = [&](int b, int hl) { return PRO + SH_WT + (size_t)b * WT_BR + hl * 131072; };
    auto W2T = [&](int b, int hl) { return PRO + SH_WT + (size_t)b * WT_BR + 262144 + hl * 131072; };
    auto WQT = [&](int b, int hl) { return PRO + SH_WT + (size_t)b * WT_BR + 524288 + hl * 65536; };
    auto WKT = [&](int b, int hl) { return PRO + SH_WT + (size_t)b * WT_BR + 655360 + hl * 65536; };
    ushort_t* WCT_H = WLT;            // combined [wloc;wglb]^T hi: [256 n][512 k]
    ushort_t* WCT_L = WLT + 131072;
    ushort_t* OUTCH = EPI;            // [4096][512] hi
    ushort_t* OUTCL = EPI + 2097152;  // [4096][512] lo

    auto QHp = [&](int b) { return QKS + (size_t)(b * 4 + 0) * 1048576; };
    auto QLp = [&](int b) { return QKS + (size_t)(b * 4 + 1) * 1048576; };
    auto KHp = [&](int b) { return QKS + (size_t)(b * 4 + 2) * 1048576; };
    auto KLp = [&](int b) { return QKS + (size_t)(b * 4 + 3) * 1048576; };

    // branch order [pe, se, ae] to match (a_*, b_*, c_*) coefficient order
    const float* Xin[3] = {(const float*)d_in[1], (const float*)d_in[2], (const float*)d_in[0]};
    const int base_idx[3] = {14, 25, 3};
    const float *w1[3], *b1[3], *w2[3], *b2[3], *gw[3], *asv[3], *adv[3], *wq[3], *bq[3], *wk[3], *bk[3];
    for (int b = 0; b < 3; ++b) {
        int o = base_idx[b];
        w1[b] = (const float*)d_in[o + 0]; b1[b] = (const float*)d_in[o + 1];
        w2[b] = (const float*)d_in[o + 2]; b2[b] = (const float*)d_in[o + 3];
        gw[b] = (const float*)d_in[o + 4]; asv[b] = (const float*)d_in[o + 5];
        adv[b] = (const float*)d_in[o + 6];
        wq[b] = (const float*)d_in[o + 7]; bq[b] = (const float*)d_in[o + 8];
        wk[b] = (const float*)d_in[o + 9]; bk[b] = (const float*)d_in[o + 10];
    }
    const float* al = (const float*)d_in[36]; const float* bl = (const float*)d_in[37];
    const float* cl = (const float*)d_in[38];
    const float* ag = (const float*)d_in[39]; const float* bg = (const float*)d_in[40];
    const float* cg = (const float*)d_in[41];
    const float* wloc = (const float*)d_in[42];
    const float* wglb = (const float*)d_in[43];
    const int* ei = (const int*)d_in[44];

    dim3 blk(256);

    // 0. zero accumulators
    hipMemsetAsync(LP, 0, (ZERO_END - OFF_LP) * sizeof(float), stream);

    // 0b. all weight transposes+splits in one batched launch (z = 14)
    {
        TArgs a{};
        for (int b = 0; b < 3; ++b) {
            a.s[b] = w1[b]; a.h[b] = W1T(b, 0); a.l[b] = W1T(b, 1);
            a.nshift[b] = 9; a.total[b] = 131072; a.kstride[b] = 256; a.koff[b] = 0;
            a.s[3 + b] = w2[b]; a.h[3 + b] = W2T(b, 0); a.l[3 + b] = W2T(b, 1);
            a.nshift[3 + b] = 8; a.total[3 + b] = 131072; a.kstride[3 + b] = 512; a.koff[3 + b] = 0;
            a.s[6 + b] = wq[b]; a.h[6 + b] = WQT(b, 0); a.l[6 + b] = WQT(b, 1);
            a.nshift[6 + b] = 8; a.total[6 + b] = 65536; a.kstride[6 + b] = 256; a.koff[6 + b] = 0;
            a.s[9 + b] = wk[b]; a.h[9 + b] = WKT(b, 0); a.l[9 + b] = WKT(b, 1);
            a.nshift[9 + b] = 8; a.total[9 + b] = 65536; a.kstride[9 + b] = 256; a.koff[9 + b] = 0;
        }
        a.s[12] = wloc; a.h[12] = WCT_H; a.l[12] = WCT_L;
        a.nshift[12] = 8; a.total[12] = 65536; a.kstride[12] = 512; a.koff[12] = 0;
        a.s[13] = wglb; a.h[13] = WCT_H; a.l[13] = WCT_L;
        a.nshift[13] = 8; a.total[13] = 65536; a.kstride[13] = 512; a.koff[13] = 256;
        wtrans_k<<<dim3(512, 1, 14), blk, 0, stream>>>(a);
    }

    // 0c. split inputs pe/se/ae -> hi/lo bf16
    split3_k<<<dim3(1024, 1, 3), blk, 0, stream>>>(Xin[0], Xin[1], Xin[2], XINH, XINL, 1048576);

    // 1. MLP1 batched (z=3): HID[b] = relu(X@w1+b1) -> split
    {
        MArgs a{};
        for (int b = 0; b < 3; ++b) {
            a.Ah[b] = XINH + (size_t)b * 1048576; a.Al[b] = XINL + (size_t)b * 1048576;
            a.Bh[b] = W1T(b, 0); a.Bl[b] = W1T(b, 1); a.bias[b] = b1[b];
            a.Cf[b] = nullptr;
            a.Ch[b] = HIDH + (size_t)b * 2097152; a.Cl[b] = HIDL + (size_t)b * 2097152;
        }
        mgemm_k<1><<<dim3(32, 8, 3), blk, 0, stream>>>(a, 512, 256);
    }
    // 1b. MLP2 batched (z=3): XM[b] = HID@w2+b2 -> fp32 + split
    {
        MArgs a{};
        for (int b = 0; b < 3; ++b) {
            a.Ah[b] = HIDH + (size_t)b * 2097152; a.Al[b] = HIDL + (size_t)b * 2097152;
            a.Bh[b] = W2T(b, 0); a.Bl[b] = W2T(b, 1); a.bias[b] = b2[b];
            a.Cf[b] = XM + (size_t)b * 1048576;
            a.Ch[b] = XMH + (size_t)b * 1048576; a.Cl[b] = XML + (size_t)b * 1048576;
        }
        mgemm_k<0><<<dim3(32, 4, 3), blk, 0, stream>>>(a, 256, 512);
    }

    // 2. GAT vecs + per-node halves + fused edge pass (wexp/adj/degree)
    gatvec_k<<<6, blk, 0, stream>>>(gw[0], gw[1], gw[2],
                                    asv[0], adv[0], asv[1], adv[1], asv[2], adv[2], WSD);
    hshd_k<<<dim3(NN, 3), blk, 0, stream>>>(XM, XM + 1048576, XM + 2 * 1048576, WSD, HS, HD);
    edge_k<<<EE / 256, blk, 0, stream>>>(ei, HS, HD, WEXP, ADJ, ECNT);

    // 2b. edge CSR by dst
    prefix_k<<<1, blk, 0, stream>>>(ECNT, EOFF, ECUR);
    efill_k<<<EE / 256, blk, 0, stream>>>(ei, ECUR, ELST);

    // 3. q/k projections batched (z=6) -> hi/lo bf16
    {
        MArgs a{};
        for (int b = 0; b < 3; ++b) {
            a.Ah[b] = XMH + (size_t)b * 1048576; a.Al[b] = XML + (size_t)b * 1048576;
            a.Bh[b] = WQT(b, 0); a.Bl[b] = WQT(b, 1); a.bias[b] = bq[b];
            a.Cf[b] = nullptr; a.Ch[b] = QHp(b); a.Cl[b] = QLp(b);
            a.Ah[3 + b] = a.Ah[b]; a.Al[3 + b] = a.Al[b];
            a.Bh[3 + b] = WKT(b, 0); a.Bl[3 + b] = WKT(b, 1); a.bias[3 + b] = bk[b];
            a.Cf[3 + b] = nullptr; a.Ch[3 + b] = KHp(b); a.Cl[3 + b] = KLp(b);
        }
        mgemm_k<0><<<dim3(32, 4, 6), blk, 0, stream>>>(a, 256, 256);
    }

    // 4. QK^T batched (z=3); ae branch rowsum-only
    {
        QArgs a{};
        for (int b = 0; b < 3; ++b) {
            a.qh[b] = QHp(b); a.ql[b] = QLp(b); a.kh[b] = KHp(b); a.kl[b] = KLp(b);
        }
        a.ept[0] = EPT; a.rs[0] = LP;
        a.ept[1] = EST; a.rs[1] = LS;
        a.ept[2] = nullptr; a.rs[2] = LA;
        qk_mfma_k<<<dim3(32, 32, 3), blk, 0, stream>>>(a, 0.0625f);
    }

    // 4b. Lp <- ag/Lp, Ls <- bg/Ls
    invrows_k<<<16, blk, 0, stream>>>(LP, LS, ag, bg);

    // 5. per-column top-32 (+fused gcount)
    topk_k<<<NN, blk, 0, stream>>>(EPT, EST, LP, LS, ADJ, TKI, TKV, GCNT);

    // 5b. global CSR offsets
    prefix_k<<<1, blk, 0, stream>>>(GCNT, GOFF, GCUR);

    // 6. sparse aw + column-normalized g values (+fused gfill)
    awcol_k<<<NN, blk, 0, stream>>>(QHp(2), QLp(2), KHp(2), KLp(2), LA,
                                    TKI, TKV, ag, bg, cg, GN, GCUR, GLST);

    // 7/8. merged gathers write split bf16 directly into K-concat [OUTL|OUTG]
    gather_k<<<NN / 2, blk, 0, stream>>>(ei, EOFF, ELST, WEXP, GOFF, GLST, GN,
                                         XM + 2 * 1048576, al, bl, cl, OUTCH, OUTCL);

    // 9. out = [OUTL|OUTG] @ [wloc;wglb]  (single K=512 MFMA GEMM)
    {
        MArgs a{};
        a.Ah[0] = OUTCH; a.Al[0] = OUTCL;
        a.Bh[0] = WCT_H; a.Bl[0] = WCT_L; a.bias[0] = nullptr;
        a.Cf[0] = (float*)d_out; a.Ch[0] = nullptr; a.Cl[0] = nullptr;
        mgemm_k<0><<<dim3(32, 4, 1), blk, 0, stream>>>(a, 256, 512);
    }
}